// Round 4
// baseline (223.486 us; speedup 1.0000x reference)
//
#include <hip/hip_runtime.h>
#include <stdint.h>
#include <stddef.h>

typedef __attribute__((ext_vector_type(4))) float  f32x4;
typedef __attribute__((ext_vector_type(8))) short  s16x8;
typedef __attribute__((ext_vector_type(4))) float  float4v;
typedef __attribute__((ext_vector_type(4))) unsigned short u16x4;

#define DIM    1024
#define HEADS  16
#define HD     64
#define SEQ    2048
#define BATCH  2
#define TOKENS (BATCH * SEQ)   // 4096

// 0.125 (1/sqrt(64)) * log2(e): folded into Q so softmax uses exp2 directly
#define QSCALE 0.18033688011112042f

// ---------- helpers ----------
__device__ __forceinline__ unsigned short f2bf(float f) {
  union { float f; uint32_t u; } x; x.f = f;
  uint32_t r = x.u + 0x7fffu + ((x.u >> 16) & 1u);   // RNE
  return (unsigned short)(r >> 16);
}

__device__ __forceinline__ float fast_exp2(float x) {
#if __has_builtin(__builtin_amdgcn_exp2f)
  return __builtin_amdgcn_exp2f(x);
#else
  return exp2f(x);
#endif
}

// async global->LDS, 16 B per lane; lds dest = base + lane*16 (wave-uniform base)
__device__ __forceinline__ void stage16(const unsigned short* gp, unsigned short* lp) {
#if __has_builtin(__builtin_amdgcn_global_load_lds)
  __builtin_amdgcn_global_load_lds((const __attribute__((address_space(1))) void*)gp,
                                   (__attribute__((address_space(3))) void*)lp, 16, 0, 0);
#else
  *(s16x8*)(lp + (threadIdx.x & 63) * 8) = *(const s16x8*)gp;
#endif
}

// ---------- fused cast fp32 -> bf16 (x, W_qkv, W_out in one launch) ----------
#define N4_X  (TOKENS * DIM / 4)
#define N4_WQ (3 * DIM * DIM / 4)
#define N4_WO (DIM * DIM / 4)
__global__ __launch_bounds__(256) void mhsa_cast_all(const float* __restrict__ x,
    const float* __restrict__ wq, const float* __restrict__ wo,
    unsigned short* __restrict__ xb, unsigned short* __restrict__ wqb,
    unsigned short* __restrict__ wob) {
  int i = blockIdx.x * 256 + threadIdx.x;
  const float* src; unsigned short* dst; int off;
  if (i < N4_X)              { src = x;  dst = xb;  off = i; }
  else if (i < N4_X + N4_WQ) { src = wq; dst = wqb; off = i - N4_X; }
  else                       { src = wo; dst = wob; off = i - (N4_X + N4_WQ); }
  float4v f = ((const float4v*)src)[off];
  u16x4 o;
  o.x = f2bf(f.x); o.y = f2bf(f.y); o.z = f2bf(f.z); o.w = f2bf(f.w);
  ((u16x4*)dst)[off] = o;
}

// ---------- QKV GEMM: C[t,e] = sum_k x[t,k]*Wqkv[e,k] + b[e]; scatter q/k/vT ----------
// 128x128 tile, BK=32, 256 threads (4 waves 2x2), global_load_lds staging (m97 pattern)
__global__ __launch_bounds__(256) void mhsa_gemm_qkv(const unsigned short* __restrict__ A,
    const unsigned short* __restrict__ Bw, const float* __restrict__ bias,
    unsigned short* __restrict__ qws, unsigned short* __restrict__ kws,
    unsigned short* __restrict__ vws) {
  __shared__ unsigned short As[128 * 32];
  __shared__ unsigned short Bs[128 * 32];
  const int t = threadIdx.x;
  const int w = t >> 6, l = t & 63;
  const int wm = w >> 1, wn = w & 1;
  const int rowBase = blockIdx.y * 128;
  const int colBase = blockIdx.x * 128;
  const int fr = l & 15, fc = (l >> 4) * 8;
  const int crow = l >> 2, ccol = (l & 3) * 8;   // within 16-row x 32-col staging chunk

  f32x4 zero = {0.f, 0.f, 0.f, 0.f};
  f32x4 acc[4][4];
  #pragma unroll
  for (int i = 0; i < 4; ++i)
    #pragma unroll
    for (int j = 0; j < 4; ++j) acc[i][j] = zero;

  for (int k0 = 0; k0 < DIM; k0 += 32) {
    __syncthreads();
    #pragma unroll
    for (int it = 0; it < 2; ++it) {
      const int c = w * 2 + it;                  // 8 chunks of 16 rows
      stage16(A  + (size_t)(rowBase + c * 16 + crow) * DIM + k0 + ccol, &As[c * 512]);
      stage16(Bw + (size_t)(colBase + c * 16 + crow) * DIM + k0 + ccol, &Bs[c * 512]);
    }
    __syncthreads();
    s16x8 af[4], bfr[4];
    #pragma unroll
    for (int i = 0; i < 4; ++i) af[i]  = *(const s16x8*)&As[(wm * 64 + i * 16 + fr) * 32 + fc];
    #pragma unroll
    for (int j = 0; j < 4; ++j) bfr[j] = *(const s16x8*)&Bs[(wn * 64 + j * 16 + fr) * 32 + fc];
    #pragma unroll
    for (int i = 0; i < 4; ++i)
      #pragma unroll
      for (int j = 0; j < 4; ++j)
        acc[i][j] = __builtin_amdgcn_mfma_f32_16x16x32_bf16(af[i], bfr[j], acc[i][j], 0, 0, 0);
  }

  const int q4 = l >> 4, ln = l & 15;
  #pragma unroll
  for (int i = 0; i < 4; ++i) {
    const int trow0 = rowBase + wm * 64 + i * 16 + q4 * 4;
    #pragma unroll
    for (int j = 0; j < 4; ++j) {
      const int e = colBase + wn * 64 + j * 16 + ln;
      const float bs = bias[e];
      const int which = e >> 10;
      const int rr = e & 1023;
      const int h = rr >> 6, d = rr & 63;
      unsigned short* dst = (which == 0) ? qws : ((which == 1) ? kws : vws);
      const float sc = (which == 0) ? QSCALE : 1.0f;   // fold attn scale + log2e into q
      #pragma unroll
      for (int r = 0; r < 4; ++r) {
        const int trow = trow0 + r;
        const int b = trow >> 11, n = trow & 2047;
        const float val = (acc[i][j][r] + bs) * sc;
        size_t idx;
        if (which == 2) idx = ((size_t)((b * HEADS + h) * HD + d)) * SEQ + n;   // V transposed [bh][d][n]
        else            idx = ((size_t)((b * HEADS + h) * SEQ + n)) * HD + d;   // Q/K [bh][n][d]
        dst[idx] = f2bf(val);
      }
    }
  }
}

// ---------- Output GEMM: out[t,e] = sum_k AO[t,k]*Wout[e,k] + b[e] (fp32 out) ----------
__global__ __launch_bounds__(256) void mhsa_gemm_out(const unsigned short* __restrict__ A,
    const unsigned short* __restrict__ Bw, const float* __restrict__ bias,
    float* __restrict__ out) {
  __shared__ unsigned short As[128 * 32];
  __shared__ unsigned short Bs[128 * 32];
  const int t = threadIdx.x;
  const int w = t >> 6, l = t & 63;
  const int wm = w >> 1, wn = w & 1;
  const int rowBase = blockIdx.y * 128;
  const int colBase = blockIdx.x * 128;
  const int fr = l & 15, fc = (l >> 4) * 8;
  const int crow = l >> 2, ccol = (l & 3) * 8;

  f32x4 zero = {0.f, 0.f, 0.f, 0.f};
  f32x4 acc[4][4];
  #pragma unroll
  for (int i = 0; i < 4; ++i)
    #pragma unroll
    for (int j = 0; j < 4; ++j) acc[i][j] = zero;

  for (int k0 = 0; k0 < DIM; k0 += 32) {
    __syncthreads();
    #pragma unroll
    for (int it = 0; it < 2; ++it) {
      const int c = w * 2 + it;
      stage16(A  + (size_t)(rowBase + c * 16 + crow) * DIM + k0 + ccol, &As[c * 512]);
      stage16(Bw + (size_t)(colBase + c * 16 + crow) * DIM + k0 + ccol, &Bs[c * 512]);
    }
    __syncthreads();
    s16x8 af[4], bfr[4];
    #pragma unroll
    for (int i = 0; i < 4; ++i) af[i]  = *(const s16x8*)&As[(wm * 64 + i * 16 + fr) * 32 + fc];
    #pragma unroll
    for (int j = 0; j < 4; ++j) bfr[j] = *(const s16x8*)&Bs[(wn * 64 + j * 16 + fr) * 32 + fc];
    #pragma unroll
    for (int i = 0; i < 4; ++i)
      #pragma unroll
      for (int j = 0; j < 4; ++j)
        acc[i][j] = __builtin_amdgcn_mfma_f32_16x16x32_bf16(af[i], bfr[j], acc[i][j], 0, 0, 0);
  }

  const int q4 = l >> 4, ln = l & 15;
  #pragma unroll
  for (int i = 0; i < 4; ++i) {
    const int trow0 = rowBase + wm * 64 + i * 16 + q4 * 4;
    #pragma unroll
    for (int j = 0; j < 4; ++j) {
      const int e = colBase + wn * 64 + j * 16 + ln;
      const float bs = bias[e];
      #pragma unroll
      for (int r = 0; r < 4; ++r)
        out[(size_t)(trow0 + r) * DIM + e] = acc[i][j][r] + bs;
    }
  }
}

// ---------- Flash attention v4: double-buffered K/V staging, one barrier/iter ----------
// 256 threads (4 waves x 32 q-rows = 128-row q-tile), K/V tiles of 64, XOR-swizzled LDS.
// Q pre-scaled by 0.125*log2e => P = exp2(S); logits bounded so no running max.
// Pipeline: [barrier] -> issue async stage of iter j+1 into nxt buf -> compute from cur
// -> [barrier]. The vmcnt(0) drain at each barrier waits on loads issued a full
// compute-phase earlier => staging latency hidden (the hipBLASLt-style fix the 2-barrier
// m97 GEMM loop cannot express).
__global__ __launch_bounds__(256, 2) void mhsa_attn(const unsigned short* __restrict__ q,
    const unsigned short* __restrict__ k, const unsigned short* __restrict__ vt,
    unsigned short* __restrict__ o) {
  __shared__ unsigned short Qs[128 * 64];       // 16 KB (read only during hoist)
  __shared__ unsigned short Ps[4 * 32 * 68];    // 17 KB per-wave P scratch (stride 68: conflict-free)
  __shared__ unsigned short Ks[2][64 * 64];     // 16 KB double-buffered K tile
  __shared__ unsigned short Vs[2][64 * 64];     // 16 KB double-buffered V^T tile
  const int t = threadIdx.x, w = t >> 6, l = t & 63;
  const int q4 = l >> 4, ln = l & 15;
  const int bh = blockIdx.y, q0 = blockIdx.x * 128;
  const unsigned short* qb  = q  + (size_t)bh * SEQ * HD;
  const unsigned short* kb  = k  + (size_t)bh * SEQ * HD;
  const unsigned short* vtb = vt + (size_t)bh * HD * SEQ;

  // staging lane geometry: slab = 8 rows x 64 cols; lane l covers row l>>3,
  // swizzled chunk l&7 -> global column ((l&7)^(l>>3))*8
  const int srow = l >> 3;
  const int scol = ((l & 7) ^ srow) * 8;

  // stage Q tile 128x64 (16 slabs; wave w does slabs w*4..w*4+3)
  #pragma unroll
  for (int it = 0; it < 4; ++it) {
    const int c = w * 4 + it;
    stage16(qb + (size_t)(q0 + c * 8 + srow) * HD + scol, &Qs[c * 512]);
  }
  // stage K/V tile 0 into buffer 0 (8 slabs each; wave w does slabs w, w+4)
  #pragma unroll
  for (int it = 0; it < 2; ++it) {
    const int c = w + it * 4;
    stage16(kb  + (size_t)(c * 8 + srow) * HD + scol, &Ks[0][c * 512]);
    stage16(vtb + (size_t)(c * 8 + srow) * SEQ + scol, &Vs[0][c * 512]);
  }
  __syncthreads();   // drains Q + buf0

  // hoist this wave's Q fragments (rows w*32 + i*16 + ln)
  s16x8 aq[2][2];
  #pragma unroll
  for (int i = 0; i < 2; ++i)
    #pragma unroll
    for (int kk = 0; kk < 2; ++kk)
      aq[i][kk] = *(const s16x8*)&Qs[(w * 32 + i * 16 + ln) * 64 + (((kk * 4 + q4) ^ (ln & 7)) * 8)];

  unsigned short* Pw = &Ps[w * (32 * 68)];
  f32x4 zero = {0.f, 0.f, 0.f, 0.f};
  f32x4 accO[2][4];
  float lsum[2][4];
  #pragma unroll
  for (int i = 0; i < 2; ++i)
    #pragma unroll
    for (int jd = 0; jd < 4; ++jd) { accO[i][jd] = zero; lsum[i][jd] = 0.f; }

  for (int jt = 0; jt < SEQ / 64; ++jt) {
    const int cur = jt & 1, nxt = cur ^ 1;
    // issue async staging for next tile immediately (hidden under this iter's compute)
    if (jt + 1 < SEQ / 64) {
      const int j1 = (jt + 1) * 64;
      #pragma unroll
      for (int it = 0; it < 2; ++it) {
        const int c = w + it * 4;
        stage16(kb  + (size_t)(j1 + c * 8 + srow) * HD + scol, &Ks[nxt][c * 512]);
        stage16(vtb + (size_t)(c * 8 + srow) * SEQ + j1 + scol, &Vs[nxt][c * 512]);
      }
    }

    // S = Q K^T (pre-scaled); B-frags loaded once, reused across both m-tiles
    f32x4 S[2][4];
    #pragma unroll
    for (int i = 0; i < 2; ++i)
      #pragma unroll
      for (int j = 0; j < 4; ++j) S[i][j] = zero;
    #pragma unroll
    for (int j = 0; j < 4; ++j) {
      s16x8 bk0 = *(const s16x8*)&Ks[cur][(j * 16 + ln) * 64 + ((q4 ^ (ln & 7)) * 8)];
      s16x8 bk1 = *(const s16x8*)&Ks[cur][(j * 16 + ln) * 64 + (((4 + q4) ^ (ln & 7)) * 8)];
      #pragma unroll
      for (int i = 0; i < 2; ++i) {
        S[i][j] = __builtin_amdgcn_mfma_f32_16x16x32_bf16(aq[i][0], bk0, S[i][j], 0, 0, 0);
        S[i][j] = __builtin_amdgcn_mfma_f32_16x16x32_bf16(aq[i][1], bk1, S[i][j], 0, 0, 0);
      }
    }

    // P = exp2(S), truncate to bf16; lsum from the SAME truncated values
    #pragma unroll
    for (int i = 0; i < 2; ++i)
      #pragma unroll
      for (int j = 0; j < 4; ++j)
        #pragma unroll
        for (int r = 0; r < 4; ++r) {
          float p = fast_exp2(S[i][j][r]);
          uint32_t u = __float_as_uint(p);
          lsum[i][r] += __uint_as_float(u & 0xffff0000u);
          Pw[(i * 16 + q4 * 4 + r) * 68 + j * 16 + ln] = (unsigned short)(u >> 16);
        }

    // hoist P A-frags once (per-wave scratch, wave-coherent; no barrier needed)
    s16x8 ap[2][2];
    #pragma unroll
    for (int i = 0; i < 2; ++i)
      #pragma unroll
      for (int kk = 0; kk < 2; ++kk)
        ap[i][kk] = *(const s16x8*)&Pw[(i * 16 + ln) * 68 + kk * 32 + q4 * 8];

    // O += P V  (Vt swizzled; B-frags loaded once, reused across both m-tiles)
    #pragma unroll
    for (int jd = 0; jd < 4; ++jd) {
      s16x8 bv0 = *(const s16x8*)&Vs[cur][(jd * 16 + ln) * 64 + ((q4 ^ (ln & 7)) * 8)];
      s16x8 bv1 = *(const s16x8*)&Vs[cur][(jd * 16 + ln) * 64 + (((4 + q4) ^ (ln & 7)) * 8)];
      #pragma unroll
      for (int i = 0; i < 2; ++i) {
        accO[i][jd] = __builtin_amdgcn_mfma_f32_16x16x32_bf16(ap[i][0], bv0, accO[i][jd], 0, 0, 0);
        accO[i][jd] = __builtin_amdgcn_mfma_f32_16x16x32_bf16(ap[i][1], bv1, accO[i][jd], 0, 0, 0);
      }
    }

    __syncthreads();   // publishes nxt staging; guards cur buffer reuse next iter
  }

  // epilogue: reduce row-sums once, normalize, store bf16 [b,n,h*64+d]
  const int b = bh >> 4, h = bh & 15;
  #pragma unroll
  for (int i = 0; i < 2; ++i)
    #pragma unroll
    for (int r = 0; r < 4; ++r) {
      float s = lsum[i][r];
      #pragma unroll
      for (int m = 1; m < 16; m <<= 1) s += __shfl_xor(s, m);
      const float inv = 1.f / s;
      const int row = q0 + w * 32 + i * 16 + q4 * 4 + r;
      #pragma unroll
      for (int jd = 0; jd < 4; ++jd)
        o[((size_t)(b * SEQ + row)) * DIM + h * HD + jd * 16 + ln] = f2bf(accO[i][jd][r] * inv);
    }
}

// ---------- launch ----------
extern "C" void kernel_launch(void* const* d_in, const int* in_sizes, int n_in,
                              void* d_out, int out_size, void* d_ws, size_t ws_size,
                              hipStream_t stream) {
  const float* x     = (const float*)d_in[0];   // [2,2048,1024]
  const float* Wqkv  = (const float*)d_in[1];   // [3072,1024]
  const float* bqkv  = (const float*)d_in[2];   // [3072]
  const float* Wout  = (const float*)d_in[3];   // [1024,1024]
  const float* bout  = (const float*)d_in[4];   // [1024]
  float* out = (float*)d_out;

  unsigned short* ws = (unsigned short*)d_ws;
  unsigned short* x_bf    = ws;
  unsigned short* wqkv_bf = x_bf    + (size_t)TOKENS * DIM;
  unsigned short* wout_bf = wqkv_bf + (size_t)3 * DIM * DIM;
  unsigned short* q_ws    = wout_bf + (size_t)DIM * DIM;
  unsigned short* k_ws    = q_ws    + (size_t)TOKENS * DIM;
  unsigned short* v_ws    = k_ws    + (size_t)TOKENS * DIM;    // transposed [bh][d][n]
  unsigned short* ao_ws   = v_ws    + (size_t)TOKENS * DIM;

  // fused cast (one launch)
  {
    const int n4 = N4_X + N4_WQ + N4_WO;   // 2,097,152 -> 8192 blocks
    mhsa_cast_all<<<n4 / 256, 256, 0, stream>>>(x, Wqkv, Wout, x_bf, wqkv_bf, wout_bf);
  }

  // QKV projection + scatter (V transposed, Q pre-scaled)
  {
    dim3 grid(3 * DIM / 128, TOKENS / 128);   // (24, 32)
    mhsa_gemm_qkv<<<grid, 256, 0, stream>>>(x_bf, wqkv_bf, bqkv, q_ws, k_ws, v_ws);
  }

  // fused attention
  {
    dim3 grid(SEQ / 128, BATCH * HEADS);      // (16, 32), 256 threads
    mhsa_attn<<<grid, 256, 0, stream>>>(q_ws, k_ws, v_ws, ao_ws);
  }

  // output projection
  {
    dim3 grid(DIM / 128, TOKENS / 128);       // (8, 32)
    mhsa_gemm_out<<<grid, 256, 0, stream>>>(ao_ws, wout_bf, bout, out);
  }
}

// Round 5
// 212.138 us; speedup vs baseline: 1.0535x; 1.0535x over previous
//
#include <hip/hip_runtime.h>
#include <stdint.h>
#include <stddef.h>

typedef __attribute__((ext_vector_type(4))) float  f32x4;
typedef __attribute__((ext_vector_type(8))) short  s16x8;
typedef __attribute__((ext_vector_type(4))) float  float4v;
typedef __attribute__((ext_vector_type(4))) unsigned short u16x4;
typedef __attribute__((ext_vector_type(2))) unsigned int   u32x2;

#define DIM    1024
#define HEADS  16
#define HD     64
#define SEQ    2048
#define BATCH  2
#define TOKENS (BATCH * SEQ)   // 4096

// 0.125 (1/sqrt(64)) * log2(e): folded into Q so softmax uses exp2 directly
#define QSCALE 0.18033688011112042f

// ---------- helpers ----------
__device__ __forceinline__ unsigned short f2bf(float f) {
  union { float f; uint32_t u; } x; x.f = f;
  uint32_t r = x.u + 0x7fffu + ((x.u >> 16) & 1u);   // RNE
  return (unsigned short)(r >> 16);
}

__device__ __forceinline__ float fast_exp2(float x) {
#if __has_builtin(__builtin_amdgcn_exp2f)
  return __builtin_amdgcn_exp2f(x);
#else
  return exp2f(x);
#endif
}

// pack high-16s of two fp32 into one dword: (hi & 0xffff0000) | (lo >> 16)
__device__ __forceinline__ uint32_t pack_bf16_trunc(uint32_t lo, uint32_t hi) {
#if __has_builtin(__builtin_amdgcn_perm)
  return __builtin_amdgcn_perm(hi, lo, 0x07060302u);
#else
  return (hi & 0xffff0000u) | (lo >> 16);
#endif
}

// async global->LDS, 16 B per lane; lds dest = base + lane*16 (wave-uniform base)
__device__ __forceinline__ void stage16(const unsigned short* gp, unsigned short* lp) {
#if __has_builtin(__builtin_amdgcn_global_load_lds)
  __builtin_amdgcn_global_load_lds((const __attribute__((address_space(1))) void*)gp,
                                   (__attribute__((address_space(3))) void*)lp, 16, 0, 0);
#else
  *(s16x8*)(lp + (threadIdx.x & 63) * 8) = *(const s16x8*)gp;
#endif
}

// ---------- fused cast fp32 -> bf16 (x, W_qkv, W_out in one launch) ----------
#define N4_X  (TOKENS * DIM / 4)
#define N4_WQ (3 * DIM * DIM / 4)
#define N4_WO (DIM * DIM / 4)
__global__ __launch_bounds__(256) void mhsa_cast_all(const float* __restrict__ x,
    const float* __restrict__ wq, const float* __restrict__ wo,
    unsigned short* __restrict__ xb, unsigned short* __restrict__ wqb,
    unsigned short* __restrict__ wob) {
  int i = blockIdx.x * 256 + threadIdx.x;
  const float* src; unsigned short* dst; int off;
  if (i < N4_X)              { src = x;  dst = xb;  off = i; }
  else if (i < N4_X + N4_WQ) { src = wq; dst = wqb; off = i - N4_X; }
  else                       { src = wo; dst = wob; off = i - (N4_X + N4_WQ); }
  float4v f = ((const float4v*)src)[off];
  u16x4 o;
  o.x = f2bf(f.x); o.y = f2bf(f.y); o.z = f2bf(f.z); o.w = f2bf(f.w);
  ((u16x4*)dst)[off] = o;
}

// ---------- QKV GEMM (operand-swapped): C^T layout, packed epilogue ----------
// acc[a][b] = mfma(W-frag a, x-frag b): col=token (lane&15), row=e (quad*4+reg)
// => per lane 4 e-consecutive values: Q/K stores pack to 8B; V coalesced scalar.
__global__ __launch_bounds__(256) void mhsa_gemm_qkv(const unsigned short* __restrict__ A,
    const unsigned short* __restrict__ Bw, const float* __restrict__ bias,
    unsigned short* __restrict__ qws, unsigned short* __restrict__ kws,
    unsigned short* __restrict__ vws) {
  __shared__ unsigned short As[128 * 32];
  __shared__ unsigned short Bs[128 * 32];
  const int t = threadIdx.x;
  const int w = t >> 6, l = t & 63;
  const int wm = w >> 1, wn = w & 1;
  const int rowBase = blockIdx.y * 128;   // tokens
  const int colBase = blockIdx.x * 128;   // e
  const int fr = l & 15, fc = (l >> 4) * 8;
  const int crow = l >> 2, ccol = (l & 3) * 8;   // 16-row x 32-col staging chunk

  f32x4 zero = {0.f, 0.f, 0.f, 0.f};
  f32x4 acc[4][4];   // [a=e-tile][b=token-tile]
  #pragma unroll
  for (int a = 0; a < 4; ++a)
    #pragma unroll
    for (int b = 0; b < 4; ++b) acc[a][b] = zero;

  for (int k0 = 0; k0 < DIM; k0 += 32) {
    __syncthreads();
    #pragma unroll
    for (int it = 0; it < 2; ++it) {
      const int c = w * 2 + it;
      stage16(A  + (size_t)(rowBase + c * 16 + crow) * DIM + k0 + ccol, &As[c * 512]);
      stage16(Bw + (size_t)(colBase + c * 16 + crow) * DIM + k0 + ccol, &Bs[c * 512]);
    }
    __syncthreads();
    s16x8 xf[4], wf[4];
    #pragma unroll
    for (int b = 0; b < 4; ++b) xf[b] = *(const s16x8*)&As[(wm * 64 + b * 16 + fr) * 32 + fc];
    #pragma unroll
    for (int a = 0; a < 4; ++a) wf[a] = *(const s16x8*)&Bs[(wn * 64 + a * 16 + fr) * 32 + fc];
    #pragma unroll
    for (int a = 0; a < 4; ++a)
      #pragma unroll
      for (int b = 0; b < 4; ++b)
        acc[a][b] = __builtin_amdgcn_mfma_f32_16x16x32_bf16(wf[a], xf[b], acc[a][b], 0, 0, 0);
  }

  const int q4 = l >> 4, ln = l & 15;
  const int which = colBase >> 10;   // 0=Q 1=K 2=V (block never straddles)
  const float sc = (which == 0) ? QSCALE : 1.0f;
  unsigned short* dst = (which == 0) ? qws : ((which == 1) ? kws : vws);

  #pragma unroll
  for (int a = 0; a < 4; ++a) {
    const int e0 = colBase + wn * 64 + a * 16 + q4 * 4;  // 4-aligned, 4 consecutive e
    const float4v bs4 = *(const float4v*)&bias[e0];
    const int rr0 = e0 & 1023;
    const int h = rr0 >> 6, d0 = rr0 & 63;               // d0..d0+3 within one head
    #pragma unroll
    for (int b = 0; b < 4; ++b) {
      const int tok = rowBase + wm * 64 + b * 16 + ln;
      const int bb = tok >> 11, n = tok & 2047;
      if (which != 2) {
        u16x4 pk;
        #pragma unroll
        for (int r = 0; r < 4; ++r) pk[r] = f2bf((acc[a][b][r] + bs4[r]) * sc);
        *(u16x4*)&dst[(((size_t)(bb * HEADS + h)) * SEQ + n) * HD + d0] = pk;
      } else {
        #pragma unroll
        for (int r = 0; r < 4; ++r)
          dst[(((size_t)(bb * HEADS + h)) * HD + d0 + r) * SEQ + n] =
              f2bf(acc[a][b][r] + bs4[r]);
      }
    }
  }
}

// ---------- Output GEMM (operand-swapped): float4 epilogue stores ----------
__global__ __launch_bounds__(256) void mhsa_gemm_out(const unsigned short* __restrict__ A,
    const unsigned short* __restrict__ Bw, const float* __restrict__ bias,
    float* __restrict__ out) {
  __shared__ unsigned short As[128 * 32];
  __shared__ unsigned short Bs[128 * 32];
  const int t = threadIdx.x;
  const int w = t >> 6, l = t & 63;
  const int wm = w >> 1, wn = w & 1;
  const int rowBase = blockIdx.y * 128;
  const int colBase = blockIdx.x * 128;
  const int fr = l & 15, fc = (l >> 4) * 8;
  const int crow = l >> 2, ccol = (l & 3) * 8;

  f32x4 zero = {0.f, 0.f, 0.f, 0.f};
  f32x4 acc[4][4];
  #pragma unroll
  for (int a = 0; a < 4; ++a)
    #pragma unroll
    for (int b = 0; b < 4; ++b) acc[a][b] = zero;

  for (int k0 = 0; k0 < DIM; k0 += 32) {
    __syncthreads();
    #pragma unroll
    for (int it = 0; it < 2; ++it) {
      const int c = w * 2 + it;
      stage16(A  + (size_t)(rowBase + c * 16 + crow) * DIM + k0 + ccol, &As[c * 512]);
      stage16(Bw + (size_t)(colBase + c * 16 + crow) * DIM + k0 + ccol, &Bs[c * 512]);
    }
    __syncthreads();
    s16x8 xf[4], wf[4];
    #pragma unroll
    for (int b = 0; b < 4; ++b) xf[b] = *(const s16x8*)&As[(wm * 64 + b * 16 + fr) * 32 + fc];
    #pragma unroll
    for (int a = 0; a < 4; ++a) wf[a] = *(const s16x8*)&Bs[(wn * 64 + a * 16 + fr) * 32 + fc];
    #pragma unroll
    for (int a = 0; a < 4; ++a)
      #pragma unroll
      for (int b = 0; b < 4; ++b)
        acc[a][b] = __builtin_amdgcn_mfma_f32_16x16x32_bf16(wf[a], xf[b], acc[a][b], 0, 0, 0);
  }

  const int q4 = l >> 4, ln = l & 15;
  #pragma unroll
  for (int a = 0; a < 4; ++a) {
    const int e0 = colBase + wn * 64 + a * 16 + q4 * 4;
    const float4v bs4 = *(const float4v*)&bias[e0];
    #pragma unroll
    for (int b = 0; b < 4; ++b) {
      const int tok = rowBase + wm * 64 + b * 16 + ln;
      float4v v;
      #pragma unroll
      for (int r = 0; r < 4; ++r) v[r] = acc[a][b][r] + bs4[r];
      *(float4v*)&out[(size_t)tok * DIM + e0] = v;
    }
  }
}

// ---------- Flash attention v5: S^T MFMA + b64 P path, dbuf K/V ----------
// 256 threads (4 waves x 32 q-rows), K/V tiles 64, XOR-swizzled staging.
// S^T = mfma(K-frag, Q-frag): C col=query, row=key => per lane 4 key-consecutive
// P values -> v_perm-packed ds_write_b64 (8/wave-iter vs 32 b16). lsum per-lane,
// one cross-quad reduce at epilogue. Q staging aliased with per-wave P scratch.
__global__ __launch_bounds__(256, 2) void mhsa_attn(const unsigned short* __restrict__ q,
    const unsigned short* __restrict__ k, const unsigned short* __restrict__ vt,
    unsigned short* __restrict__ o) {
  __shared__ unsigned short QPs[4 * 32 * 72];   // per-wave 2304: Q staged (2048) then P (32x72)
  __shared__ unsigned short Ks[2][64 * 64];     // double-buffered K tile
  __shared__ unsigned short Vs[2][64 * 64];     // double-buffered V^T tile
  const int t = threadIdx.x, w = t >> 6, l = t & 63;
  const int q4 = l >> 4, ln = l & 15;
  const int bh = blockIdx.y, q0 = blockIdx.x * 128;
  const unsigned short* qb  = q  + (size_t)bh * SEQ * HD;
  const unsigned short* kb  = k  + (size_t)bh * SEQ * HD;
  const unsigned short* vtb = vt + (size_t)bh * HD * SEQ;

  // staging lane geometry: slab = 8 rows x 64 cols; lane l covers row l>>3,
  // swizzled chunk l&7 -> global column ((l&7)^(l>>3))*8
  const int srow = l >> 3;
  const int scol = ((l & 7) ^ srow) * 8;

  unsigned short* Pw = &QPs[w * (32 * 72)];

  // stage this wave's 32 Q rows into its own region (wave-local => no alias hazard)
  #pragma unroll
  for (int it = 0; it < 4; ++it)
    stage16(qb + (size_t)(q0 + w * 32 + it * 8 + srow) * HD + scol, &Pw[it * 512]);
  // stage K/V tile 0 into buffer 0
  #pragma unroll
  for (int it = 0; it < 2; ++it) {
    const int c = w + it * 4;
    stage16(kb  + (size_t)(c * 8 + srow) * HD + scol, &Ks[0][c * 512]);
    stage16(vtb + (size_t)(c * 8 + srow) * SEQ + scol, &Vs[0][c * 512]);
  }
  __syncthreads();   // drains Q + buf0

  // hoist Q fragments (local rows i*16+ln); identical bytes serve as B operand
  s16x8 aq[2][2];
  #pragma unroll
  for (int i = 0; i < 2; ++i)
    #pragma unroll
    for (int kk = 0; kk < 2; ++kk)
      aq[i][kk] = *(const s16x8*)&Pw[(i * 16 + ln) * 64 + (((kk * 4 + q4) ^ (ln & 7)) * 8)];

  f32x4 zero = {0.f, 0.f, 0.f, 0.f};
  f32x4 accO[2][4];
  float lsum[2] = {0.f, 0.f};
  #pragma unroll
  for (int i = 0; i < 2; ++i)
    #pragma unroll
    for (int jd = 0; jd < 4; ++jd) accO[i][jd] = zero;

  for (int jt = 0; jt < SEQ / 64; ++jt) {
    const int cur = jt & 1, nxt = cur ^ 1;
    // async staging of next K/V tile (hidden under this iter's compute)
    if (jt + 1 < SEQ / 64) {
      const int j1 = (jt + 1) * 64;
      #pragma unroll
      for (int it = 0; it < 2; ++it) {
        const int c = w + it * 4;
        stage16(kb  + (size_t)(j1 + c * 8 + srow) * HD + scol, &Ks[nxt][c * 512]);
        stage16(vtb + (size_t)(c * 8 + srow) * SEQ + j1 + scol, &Vs[nxt][c * 512]);
      }
    }

    // S^T = K·Q^T: A = K-frag, B = Q-frag. C: col=query(ln), row=key(q4*4+r)
    f32x4 St[4][2];   // [jb=key-block][i=query-tile]
    #pragma unroll
    for (int jb = 0; jb < 4; ++jb)
      #pragma unroll
      for (int i = 0; i < 2; ++i) St[jb][i] = zero;
    #pragma unroll
    for (int jb = 0; jb < 4; ++jb) {
      s16x8 ak0 = *(const s16x8*)&Ks[cur][(jb * 16 + ln) * 64 + ((q4 ^ (ln & 7)) * 8)];
      s16x8 ak1 = *(const s16x8*)&Ks[cur][(jb * 16 + ln) * 64 + (((4 + q4) ^ (ln & 7)) * 8)];
      #pragma unroll
      for (int i = 0; i < 2; ++i) {
        St[jb][i] = __builtin_amdgcn_mfma_f32_16x16x32_bf16(ak0, aq[i][0], St[jb][i], 0, 0, 0);
        St[jb][i] = __builtin_amdgcn_mfma_f32_16x16x32_bf16(ak1, aq[i][1], St[jb][i], 0, 0, 0);
      }
    }

    // P = exp2(S), truncate; pack 4 key-consecutive bf16 -> one b64 LDS write.
    // lsum accumulates the SAME truncated values (per-lane partial over its keys).
    #pragma unroll
    for (int i = 0; i < 2; ++i)
      #pragma unroll
      for (int jb = 0; jb < 4; ++jb) {
        uint32_t u0 = __float_as_uint(fast_exp2(St[jb][i][0]));
        uint32_t u1 = __float_as_uint(fast_exp2(St[jb][i][1]));
        uint32_t u2 = __float_as_uint(fast_exp2(St[jb][i][2]));
        uint32_t u3 = __float_as_uint(fast_exp2(St[jb][i][3]));
        lsum[i] += __uint_as_float(u0 & 0xffff0000u) + __uint_as_float(u1 & 0xffff0000u)
                 + __uint_as_float(u2 & 0xffff0000u) + __uint_as_float(u3 & 0xffff0000u);
        u32x2 pk;
        pk.x = pack_bf16_trunc(u0, u1);
        pk.y = pack_bf16_trunc(u2, u3);
        *(u32x2*)&Pw[(i * 16 + ln) * 72 + jb * 16 + q4 * 4] = pk;
      }

    // A-frags of P (row=query, stride-72: uniform bank spread, wave-local so no barrier)
    s16x8 ap[2][2];
    #pragma unroll
    for (int i = 0; i < 2; ++i)
      #pragma unroll
      for (int kk = 0; kk < 2; ++kk)
        ap[i][kk] = *(const s16x8*)&Pw[(i * 16 + ln) * 72 + kk * 32 + q4 * 8];

    // O += P V
    #pragma unroll
    for (int jd = 0; jd < 4; ++jd) {
      s16x8 bv0 = *(const s16x8*)&Vs[cur][(jd * 16 + ln) * 64 + ((q4 ^ (ln & 7)) * 8)];
      s16x8 bv1 = *(const s16x8*)&Vs[cur][(jd * 16 + ln) * 64 + (((4 + q4) ^ (ln & 7)) * 8)];
      #pragma unroll
      for (int i = 0; i < 2; ++i) {
        accO[i][jd] = __builtin_amdgcn_mfma_f32_16x16x32_bf16(ap[i][0], bv0, accO[i][jd], 0, 0, 0);
        accO[i][jd] = __builtin_amdgcn_mfma_f32_16x16x32_bf16(ap[i][1], bv1, accO[i][jd], 0, 0, 0);
      }
    }

    __syncthreads();   // publishes nxt staging; guards cur buffer reuse next iter
  }

  // epilogue: cross-quad row-sum reduce, redistribute inverse, normalize, store
  const int b = bh >> 4, h = bh & 15;
  #pragma unroll
  for (int i = 0; i < 2; ++i) {
    float s = lsum[i];
    s += __shfl_xor(s, 16);
    s += __shfl_xor(s, 32);
    const float inv = 1.f / s;      // lane holds inv for query i*16+ln
    #pragma unroll
    for (int r = 0; r < 4; ++r) {
      // accO rows are queries q4*4+r -> fetch inv from lane with ln = q4*4+r (own quad)
      const float invr = __shfl(inv, (l & 48) + q4 * 4 + r);
      const int row = q0 + w * 32 + i * 16 + q4 * 4 + r;
      #pragma unroll
      for (int jd = 0; jd < 4; ++jd)
        o[((size_t)(b * SEQ + row)) * DIM + h * HD + jd * 16 + ln] = f2bf(accO[i][jd][r] * invr);
    }
  }
}

// ---------- launch ----------
extern "C" void kernel_launch(void* const* d_in, const int* in_sizes, int n_in,
                              void* d_out, int out_size, void* d_ws, size_t ws_size,
                              hipStream_t stream) {
  const float* x     = (const float*)d_in[0];   // [2,2048,1024]
  const float* Wqkv  = (const float*)d_in[1];   // [3072,1024]
  const float* bqkv  = (const float*)d_in[2];   // [3072]
  const float* Wout  = (const float*)d_in[3];   // [1024,1024]
  const float* bout  = (const float*)d_in[4];   // [1024]
  float* out = (float*)d_out;

  unsigned short* ws = (unsigned short*)d_ws;
  unsigned short* x_bf    = ws;
  unsigned short* wqkv_bf = x_bf    + (size_t)TOKENS * DIM;
  unsigned short* wout_bf = wqkv_bf + (size_t)3 * DIM * DIM;
  unsigned short* q_ws    = wout_bf + (size_t)DIM * DIM;
  unsigned short* k_ws    = q_ws    + (size_t)TOKENS * DIM;
  unsigned short* v_ws    = k_ws    + (size_t)TOKENS * DIM;    // transposed [bh][d][n]
  unsigned short* ao_ws   = v_ws    + (size_t)TOKENS * DIM;

  // fused cast (one launch)
  {
    const int n4 = N4_X + N4_WQ + N4_WO;   // 2,097,152 -> 8192 blocks
    mhsa_cast_all<<<n4 / 256, 256, 0, stream>>>(x, Wqkv, Wout, x_bf, wqkv_bf, wout_bf);
  }

  // QKV projection + scatter (V transposed, Q pre-scaled)
  {
    dim3 grid(3 * DIM / 128, TOKENS / 128);   // (24, 32)
    mhsa_gemm_qkv<<<grid, 256, 0, stream>>>(x_bf, wqkv_bf, bqkv, q_ws, k_ws, v_ws);
  }

  // fused attention
  {
    dim3 grid(SEQ / 128, BATCH * HEADS);      // (16, 32), 256 threads
    mhsa_attn<<<grid, 256, 0, stream>>>(q_ws, k_ws, v_ws, ao_ws);
  }

  // output projection
  {
    dim3 grid(DIM / 128, TOKENS / 128);       // (8, 32)
    mhsa_gemm_out<<<grid, 256, 0, stream>>>(ao_ws, wout_bf, bout, out);
  }
}

// Round 6
// 210.174 us; speedup vs baseline: 1.0633x; 1.0093x over previous
//
#include <hip/hip_runtime.h>
#include <stdint.h>
#include <stddef.h>

typedef __attribute__((ext_vector_type(4))) float  f32x4;
typedef __attribute__((ext_vector_type(8))) short  s16x8;
typedef __attribute__((ext_vector_type(4))) float  float4v;
typedef __attribute__((ext_vector_type(4))) unsigned short u16x4;
typedef __attribute__((ext_vector_type(2))) unsigned int   u32x2;

#define DIM    1024
#define HEADS  16
#define HD     64
#define SEQ    2048
#define BATCH  2
#define TOKENS (BATCH * SEQ)   // 4096

// 0.125 (1/sqrt(64)) * log2(e): folded into Q so softmax uses exp2 directly
#define QSCALE 0.18033688011112042f

// ---------- helpers ----------
__device__ __forceinline__ unsigned short f2bf(float f) {
  union { float f; uint32_t u; } x; x.f = f;
  uint32_t r = x.u + 0x7fffu + ((x.u >> 16) & 1u);   // RNE
  return (unsigned short)(r >> 16);
}

__device__ __forceinline__ float fast_exp2(float x) {
#if __has_builtin(__builtin_amdgcn_exp2f)
  return __builtin_amdgcn_exp2f(x);
#else
  return exp2f(x);
#endif
}

// pack high-16s of two fp32 into one dword: (hi & 0xffff0000) | (lo >> 16)
__device__ __forceinline__ uint32_t pack_bf16_trunc(uint32_t lo, uint32_t hi) {
#if __has_builtin(__builtin_amdgcn_perm)
  return __builtin_amdgcn_perm(hi, lo, 0x07060302u);
#else
  return (hi & 0xffff0000u) | (lo >> 16);
#endif
}

// async global->LDS, 16 B per lane; lds dest = base + lane*16 (wave-uniform base)
__device__ __forceinline__ void stage16(const unsigned short* gp, unsigned short* lp) {
#if __has_builtin(__builtin_amdgcn_global_load_lds)
  __builtin_amdgcn_global_load_lds((const __attribute__((address_space(1))) void*)gp,
                                   (__attribute__((address_space(3))) void*)lp, 16, 0, 0);
#else
  *(s16x8*)(lp + (threadIdx.x & 63) * 8) = *(const s16x8*)gp;
#endif
}

// ---------- fused cast fp32 -> bf16 (x, W_qkv, W_out in one launch) ----------
#define N4_X  (TOKENS * DIM / 4)
#define N4_WQ (3 * DIM * DIM / 4)
#define N4_WO (DIM * DIM / 4)
__global__ __launch_bounds__(256) void mhsa_cast_all(const float* __restrict__ x,
    const float* __restrict__ wq, const float* __restrict__ wo,
    unsigned short* __restrict__ xb, unsigned short* __restrict__ wqb,
    unsigned short* __restrict__ wob) {
  int i = blockIdx.x * 256 + threadIdx.x;
  const float* src; unsigned short* dst; int off;
  if (i < N4_X)              { src = x;  dst = xb;  off = i; }
  else if (i < N4_X + N4_WQ) { src = wq; dst = wqb; off = i - N4_X; }
  else                       { src = wo; dst = wob; off = i - (N4_X + N4_WQ); }
  float4v f = ((const float4v*)src)[off];
  u16x4 o;
  o.x = f2bf(f.x); o.y = f2bf(f.y); o.z = f2bf(f.z); o.w = f2bf(f.w);
  ((u16x4*)dst)[off] = o;
}

// ================= GEMM core v2: BK=64, dbuf staging, 1 barrier/iter =================
// 128x128 tile, 256 threads (4 waves 2x2). XOR-swizzled rows (8 chunks of 16B per
// 64-elem row, chunk c of row r at slot c^(r&7)): 64-elem row = 32 dwords => swizzled
// b128 frag reads hit each bank exactly 2x (free). Staging for iter k+1 issued before
// compute of iter k; single barrier drains it after a full compute phase (attn-v4
// pipeline — the fix the m97 2-barrier loop can't express).
//
// Staging geometry: slab = 8 rows x 64 cols (one wave-instr = 1024B); lane l covers
// row l>>3, swizzled chunk l&7 -> global column ((l&7)^(l>>3))*8.

// ---------- QKV GEMM (operand-swapped): C^T layout, packed epilogue ----------
__global__ __launch_bounds__(256) void mhsa_gemm_qkv(const unsigned short* __restrict__ A,
    const unsigned short* __restrict__ Bw, const float* __restrict__ bias,
    unsigned short* __restrict__ qws, unsigned short* __restrict__ kws,
    unsigned short* __restrict__ vws) {
  __shared__ unsigned short As[2][128 * 64];
  __shared__ unsigned short Bs[2][128 * 64];
  const int t = threadIdx.x;
  const int w = t >> 6, l = t & 63;
  const int wm = w >> 1, wn = w & 1;
  const int rowBase = blockIdx.y * 128;   // tokens
  const int colBase = blockIdx.x * 128;   // e
  const int fr = l & 15, q4 = l >> 4, ln = l & 15;
  const int srow = l >> 3;
  const int scol = ((l & 7) ^ srow) * 8;

  f32x4 zero = {0.f, 0.f, 0.f, 0.f};
  f32x4 acc[4][4];   // [a=e-tile][b=token-tile]
  #pragma unroll
  for (int a = 0; a < 4; ++a)
    #pragma unroll
    for (int b = 0; b < 4; ++b) acc[a][b] = zero;

  // prologue: stage k-tile 0 into buf 0 (16 slabs each; wave w does slabs w*4..w*4+3)
  #pragma unroll
  for (int it = 0; it < 4; ++it) {
    const int c = w * 4 + it;
    stage16(A  + (size_t)(rowBase + c * 8 + srow) * DIM + scol, &As[0][c * 512]);
    stage16(Bw + (size_t)(colBase + c * 8 + srow) * DIM + scol, &Bs[0][c * 512]);
  }
  __syncthreads();

  for (int kt = 0; kt < DIM / 64; ++kt) {
    const int cur = kt & 1, nxt = cur ^ 1;
    if (kt + 1 < DIM / 64) {
      const int k1 = (kt + 1) * 64;
      #pragma unroll
      for (int it = 0; it < 4; ++it) {
        const int c = w * 4 + it;
        stage16(A  + (size_t)(rowBase + c * 8 + srow) * DIM + k1 + scol, &As[nxt][c * 512]);
        stage16(Bw + (size_t)(colBase + c * 8 + srow) * DIM + k1 + scol, &Bs[nxt][c * 512]);
      }
    }
    #pragma unroll
    for (int kk = 0; kk < 2; ++kk) {
      s16x8 xf[4], wf[4];
      #pragma unroll
      for (int b = 0; b < 4; ++b)
        xf[b] = *(const s16x8*)&As[cur][(wm * 64 + b * 16 + fr) * 64 + (((kk * 4 + q4) ^ (fr & 7)) * 8)];
      #pragma unroll
      for (int a = 0; a < 4; ++a)
        wf[a] = *(const s16x8*)&Bs[cur][(wn * 64 + a * 16 + fr) * 64 + (((kk * 4 + q4) ^ (fr & 7)) * 8)];
      #pragma unroll
      for (int a = 0; a < 4; ++a)
        #pragma unroll
        for (int b = 0; b < 4; ++b)
          acc[a][b] = __builtin_amdgcn_mfma_f32_16x16x32_bf16(wf[a], xf[b], acc[a][b], 0, 0, 0);
    }
    __syncthreads();   // publishes nxt staging; guards cur buffer reuse next iter
  }

  const int which = colBase >> 10;   // 0=Q 1=K 2=V (block never straddles)
  const float sc = (which == 0) ? QSCALE : 1.0f;
  unsigned short* dst = (which == 0) ? qws : ((which == 1) ? kws : vws);

  #pragma unroll
  for (int a = 0; a < 4; ++a) {
    const int e0 = colBase + wn * 64 + a * 16 + q4 * 4;  // 4-aligned, 4 consecutive e
    const float4v bs4 = *(const float4v*)&bias[e0];
    const int rr0 = e0 & 1023;
    const int h = rr0 >> 6, d0 = rr0 & 63;               // d0..d0+3 within one head
    #pragma unroll
    for (int b = 0; b < 4; ++b) {
      const int tok = rowBase + wm * 64 + b * 16 + ln;
      const int bb = tok >> 11, n = tok & 2047;
      if (which != 2) {
        u16x4 pk;
        #pragma unroll
        for (int r = 0; r < 4; ++r) pk[r] = f2bf((acc[a][b][r] + bs4[r]) * sc);
        *(u16x4*)&dst[(((size_t)(bb * HEADS + h)) * SEQ + n) * HD + d0] = pk;
      } else {
        #pragma unroll
        for (int r = 0; r < 4; ++r)
          dst[(((size_t)(bb * HEADS + h)) * HD + d0 + r) * SEQ + n] =
              f2bf(acc[a][b][r] + bs4[r]);
      }
    }
  }
}

// ---------- Output GEMM (operand-swapped): float4 epilogue stores ----------
__global__ __launch_bounds__(256) void mhsa_gemm_out(const unsigned short* __restrict__ A,
    const unsigned short* __restrict__ Bw, const float* __restrict__ bias,
    float* __restrict__ out) {
  __shared__ unsigned short As[2][128 * 64];
  __shared__ unsigned short Bs[2][128 * 64];
  const int t = threadIdx.x;
  const int w = t >> 6, l = t & 63;
  const int wm = w >> 1, wn = w & 1;
  const int rowBase = blockIdx.y * 128;
  const int colBase = blockIdx.x * 128;
  const int fr = l & 15, q4 = l >> 4, ln = l & 15;
  const int srow = l >> 3;
  const int scol = ((l & 7) ^ srow) * 8;

  f32x4 zero = {0.f, 0.f, 0.f, 0.f};
  f32x4 acc[4][4];
  #pragma unroll
  for (int a = 0; a < 4; ++a)
    #pragma unroll
    for (int b = 0; b < 4; ++b) acc[a][b] = zero;

  #pragma unroll
  for (int it = 0; it < 4; ++it) {
    const int c = w * 4 + it;
    stage16(A  + (size_t)(rowBase + c * 8 + srow) * DIM + scol, &As[0][c * 512]);
    stage16(Bw + (size_t)(colBase + c * 8 + srow) * DIM + scol, &Bs[0][c * 512]);
  }
  __syncthreads();

  for (int kt = 0; kt < DIM / 64; ++kt) {
    const int cur = kt & 1, nxt = cur ^ 1;
    if (kt + 1 < DIM / 64) {
      const int k1 = (kt + 1) * 64;
      #pragma unroll
      for (int it = 0; it < 4; ++it) {
        const int c = w * 4 + it;
        stage16(A  + (size_t)(rowBase + c * 8 + srow) * DIM + k1 + scol, &As[nxt][c * 512]);
        stage16(Bw + (size_t)(colBase + c * 8 + srow) * DIM + k1 + scol, &Bs[nxt][c * 512]);
      }
    }
    #pragma unroll
    for (int kk = 0; kk < 2; ++kk) {
      s16x8 xf[4], wf[4];
      #pragma unroll
      for (int b = 0; b < 4; ++b)
        xf[b] = *(const s16x8*)&As[cur][(wm * 64 + b * 16 + fr) * 64 + (((kk * 4 + q4) ^ (fr & 7)) * 8)];
      #pragma unroll
      for (int a = 0; a < 4; ++a)
        wf[a] = *(const s16x8*)&Bs[cur][(wn * 64 + a * 16 + fr) * 64 + (((kk * 4 + q4) ^ (fr & 7)) * 8)];
      #pragma unroll
      for (int a = 0; a < 4; ++a)
        #pragma unroll
        for (int b = 0; b < 4; ++b)
          acc[a][b] = __builtin_amdgcn_mfma_f32_16x16x32_bf16(wf[a], xf[b], acc[a][b], 0, 0, 0);
    }
    __syncthreads();
  }

  #pragma unroll
  for (int a = 0; a < 4; ++a) {
    const int e0 = colBase + wn * 64 + a * 16 + q4 * 4;
    const float4v bs4 = *(const float4v*)&bias[e0];
    #pragma unroll
    for (int b = 0; b < 4; ++b) {
      const int tok = rowBase + wm * 64 + b * 16 + ln;
      float4v v;
      #pragma unroll
      for (int r = 0; r < 4; ++r) v[r] = acc[a][b][r] + bs4[r];
      *(float4v*)&out[(size_t)tok * DIM + e0] = v;
    }
  }
}

// ---------- Flash attention v5 (unchanged from round 5) ----------
__global__ __launch_bounds__(256, 2) void mhsa_attn(const unsigned short* __restrict__ q,
    const unsigned short* __restrict__ k, const unsigned short* __restrict__ vt,
    unsigned short* __restrict__ o) {
  __shared__ unsigned short QPs[4 * 32 * 72];   // per-wave 2304: Q staged (2048) then P (32x72)
  __shared__ unsigned short Ks[2][64 * 64];     // double-buffered K tile
  __shared__ unsigned short Vs[2][64 * 64];     // double-buffered V^T tile
  const int t = threadIdx.x, w = t >> 6, l = t & 63;
  const int q4 = l >> 4, ln = l & 15;
  const int bh = blockIdx.y, q0 = blockIdx.x * 128;
  const unsigned short* qb  = q  + (size_t)bh * SEQ * HD;
  const unsigned short* kb  = k  + (size_t)bh * SEQ * HD;
  const unsigned short* vtb = vt + (size_t)bh * HD * SEQ;

  const int srow = l >> 3;
  const int scol = ((l & 7) ^ srow) * 8;

  unsigned short* Pw = &QPs[w * (32 * 72)];

  #pragma unroll
  for (int it = 0; it < 4; ++it)
    stage16(qb + (size_t)(q0 + w * 32 + it * 8 + srow) * HD + scol, &Pw[it * 512]);
  #pragma unroll
  for (int it = 0; it < 2; ++it) {
    const int c = w + it * 4;
    stage16(kb  + (size_t)(c * 8 + srow) * HD + scol, &Ks[0][c * 512]);
    stage16(vtb + (size_t)(c * 8 + srow) * SEQ + scol, &Vs[0][c * 512]);
  }
  __syncthreads();   // drains Q + buf0

  s16x8 aq[2][2];
  #pragma unroll
  for (int i = 0; i < 2; ++i)
    #pragma unroll
    for (int kk = 0; kk < 2; ++kk)
      aq[i][kk] = *(const s16x8*)&Pw[(i * 16 + ln) * 64 + (((kk * 4 + q4) ^ (ln & 7)) * 8)];

  f32x4 zero = {0.f, 0.f, 0.f, 0.f};
  f32x4 accO[2][4];
  float lsum[2] = {0.f, 0.f};
  #pragma unroll
  for (int i = 0; i < 2; ++i)
    #pragma unroll
    for (int jd = 0; jd < 4; ++jd) accO[i][jd] = zero;

  for (int jt = 0; jt < SEQ / 64; ++jt) {
    const int cur = jt & 1, nxt = cur ^ 1;
    if (jt + 1 < SEQ / 64) {
      const int j1 = (jt + 1) * 64;
      #pragma unroll
      for (int it = 0; it < 2; ++it) {
        const int c = w + it * 4;
        stage16(kb  + (size_t)(j1 + c * 8 + srow) * HD + scol, &Ks[nxt][c * 512]);
        stage16(vtb + (size_t)(c * 8 + srow) * SEQ + j1 + scol, &Vs[nxt][c * 512]);
      }
    }

    // S^T = K·Q^T: A = K-frag, B = Q-frag. C: col=query(ln), row=key(q4*4+r)
    f32x4 St[4][2];
    #pragma unroll
    for (int jb = 0; jb < 4; ++jb)
      #pragma unroll
      for (int i = 0; i < 2; ++i) St[jb][i] = zero;
    #pragma unroll
    for (int jb = 0; jb < 4; ++jb) {
      s16x8 ak0 = *(const s16x8*)&Ks[cur][(jb * 16 + ln) * 64 + ((q4 ^ (ln & 7)) * 8)];
      s16x8 ak1 = *(const s16x8*)&Ks[cur][(jb * 16 + ln) * 64 + (((4 + q4) ^ (ln & 7)) * 8)];
      #pragma unroll
      for (int i = 0; i < 2; ++i) {
        St[jb][i] = __builtin_amdgcn_mfma_f32_16x16x32_bf16(ak0, aq[i][0], St[jb][i], 0, 0, 0);
        St[jb][i] = __builtin_amdgcn_mfma_f32_16x16x32_bf16(ak1, aq[i][1], St[jb][i], 0, 0, 0);
      }
    }

    // P = exp2(S), truncate; pack 4 key-consecutive bf16 -> one b64 LDS write.
    #pragma unroll
    for (int i = 0; i < 2; ++i)
      #pragma unroll
      for (int jb = 0; jb < 4; ++jb) {
        uint32_t u0 = __float_as_uint(fast_exp2(St[jb][i][0]));
        uint32_t u1 = __float_as_uint(fast_exp2(St[jb][i][1]));
        uint32_t u2 = __float_as_uint(fast_exp2(St[jb][i][2]));
        uint32_t u3 = __float_as_uint(fast_exp2(St[jb][i][3]));
        lsum[i] += __uint_as_float(u0 & 0xffff0000u) + __uint_as_float(u1 & 0xffff0000u)
                 + __uint_as_float(u2 & 0xffff0000u) + __uint_as_float(u3 & 0xffff0000u);
        u32x2 pk;
        pk.x = pack_bf16_trunc(u0, u1);
        pk.y = pack_bf16_trunc(u2, u3);
        *(u32x2*)&Pw[(i * 16 + ln) * 72 + jb * 16 + q4 * 4] = pk;
      }

    s16x8 ap[2][2];
    #pragma unroll
    for (int i = 0; i < 2; ++i)
      #pragma unroll
      for (int kk = 0; kk < 2; ++kk)
        ap[i][kk] = *(const s16x8*)&Pw[(i * 16 + ln) * 72 + kk * 32 + q4 * 8];

    #pragma unroll
    for (int jd = 0; jd < 4; ++jd) {
      s16x8 bv0 = *(const s16x8*)&Vs[cur][(jd * 16 + ln) * 64 + ((q4 ^ (ln & 7)) * 8)];
      s16x8 bv1 = *(const s16x8*)&Vs[cur][(jd * 16 + ln) * 64 + (((4 + q4) ^ (ln & 7)) * 8)];
      #pragma unroll
      for (int i = 0; i < 2; ++i) {
        accO[i][jd] = __builtin_amdgcn_mfma_f32_16x16x32_bf16(ap[i][0], bv0, accO[i][jd], 0, 0, 0);
        accO[i][jd] = __builtin_amdgcn_mfma_f32_16x16x32_bf16(ap[i][1], bv1, accO[i][jd], 0, 0, 0);
      }
    }

    __syncthreads();
  }

  const int b = bh >> 4, h = bh & 15;
  #pragma unroll
  for (int i = 0; i < 2; ++i) {
    float s = lsum[i];
    s += __shfl_xor(s, 16);
    s += __shfl_xor(s, 32);
    const float inv = 1.f / s;
    #pragma unroll
    for (int r = 0; r < 4; ++r) {
      const float invr = __shfl(inv, (l & 48) + q4 * 4 + r);
      const int row = q0 + w * 32 + i * 16 + q4 * 4 + r;
      #pragma unroll
      for (int jd = 0; jd < 4; ++jd)
        o[((size_t)(b * SEQ + row)) * DIM + h * HD + jd * 16 + ln] = f2bf(accO[i][jd][r] * invr);
    }
  }
}

// ---------- launch ----------
extern "C" void kernel_launch(void* const* d_in, const int* in_sizes, int n_in,
                              void* d_out, int out_size, void* d_ws, size_t ws_size,
                              hipStream_t stream) {
  const float* x     = (const float*)d_in[0];   // [2,2048,1024]
  const float* Wqkv  = (const float*)d_in[1];   // [3072,1024]
  const float* bqkv  = (const float*)d_in[2];   // [3072]
  const float* Wout  = (const float*)d_in[3];   // [1024,1024]
  const float* bout  = (const float*)d_in[4];   // [1024]
  float* out = (float*)d_out;

  unsigned short* ws = (unsigned short*)d_ws;
  unsigned short* x_bf    = ws;
  unsigned short* wqkv_bf = x_bf    + (size_t)TOKENS * DIM;
  unsigned short* wout_bf = wqkv_bf + (size_t)3 * DIM * DIM;
  unsigned short* q_ws    = wout_bf + (size_t)DIM * DIM;
  unsigned short* k_ws    = q_ws    + (size_t)TOKENS * DIM;
  unsigned short* v_ws    = k_ws    + (size_t)TOKENS * DIM;    // transposed [bh][d][n]
  unsigned short* ao_ws   = v_ws    + (size_t)TOKENS * DIM;

  // fused cast (one launch)
  {
    const int n4 = N4_X + N4_WQ + N4_WO;   // 2,097,152 -> 8192 blocks
    mhsa_cast_all<<<n4 / 256, 256, 0, stream>>>(x, Wqkv, Wout, x_bf, wqkv_bf, wout_bf);
  }

  // QKV projection + scatter (V transposed, Q pre-scaled)
  {
    dim3 grid(3 * DIM / 128, TOKENS / 128);   // (24, 32)
    mhsa_gemm_qkv<<<grid, 256, 0, stream>>>(x_bf, wqkv_bf, bqkv, q_ws, k_ws, v_ws);
  }

  // fused attention
  {
    dim3 grid(SEQ / 128, BATCH * HEADS);      // (16, 32), 256 threads
    mhsa_attn<<<grid, 256, 0, stream>>>(q_ws, k_ws, v_ws, ao_ws);
  }

  // output projection
  {
    dim3 grid(DIM / 128, TOKENS / 128);       // (8, 32)
    mhsa_gemm_out<<<grid, 256, 0, stream>>>(ao_ws, wout_bf, bout, out);
  }
}

// Round 7
// 200.588 us; speedup vs baseline: 1.1142x; 1.0478x over previous
//
#include <hip/hip_runtime.h>
#include <stdint.h>
#include <stddef.h>

typedef __attribute__((ext_vector_type(4))) float  f32x4;
typedef __attribute__((ext_vector_type(8))) short  s16x8;
typedef __attribute__((ext_vector_type(4))) float  float4v;
typedef __attribute__((ext_vector_type(4))) unsigned short u16x4;
typedef __attribute__((ext_vector_type(2))) unsigned int   u32x2;

#define DIM    1024
#define HEADS  16
#define HD     64
#define SEQ    2048
#define BATCH  2
#define TOKENS (BATCH * SEQ)   // 4096

// 0.125 (1/sqrt(64)) * log2(e): folded into Q so softmax uses exp2 directly
#define QSCALE 0.18033688011112042f

// ---------- helpers ----------
__device__ __forceinline__ unsigned short f2bf(float f) {
  union { float f; uint32_t u; } x; x.f = f;
  uint32_t r = x.u + 0x7fffu + ((x.u >> 16) & 1u);   // RNE
  return (unsigned short)(r >> 16);
}

__device__ __forceinline__ float fast_exp2(float x) {
#if __has_builtin(__builtin_amdgcn_exp2f)
  return __builtin_amdgcn_exp2f(x);
#else
  return exp2f(x);
#endif
}

// pack high-16s of two fp32 into one dword: (hi & 0xffff0000) | (lo >> 16)
__device__ __forceinline__ uint32_t pack_bf16_trunc(uint32_t lo, uint32_t hi) {
#if __has_builtin(__builtin_amdgcn_perm)
  return __builtin_amdgcn_perm(hi, lo, 0x07060302u);
#else
  return (hi & 0xffff0000u) | (lo >> 16);
#endif
}

// async global->LDS, 16 B per lane; lds dest = base + lane*16 (wave-uniform base)
__device__ __forceinline__ void stage16(const unsigned short* gp, unsigned short* lp) {
#if __has_builtin(__builtin_amdgcn_global_load_lds)
  __builtin_amdgcn_global_load_lds((const __attribute__((address_space(1))) void*)gp,
                                   (__attribute__((address_space(3))) void*)lp, 16, 0, 0);
#else
  *(s16x8*)(lp + (threadIdx.x & 63) * 8) = *(const s16x8*)gp;
#endif
}

// ---------- fused cast fp32 -> bf16 (x, W_qkv, W_out in one launch) ----------
#define N4_X  (TOKENS * DIM / 4)
#define N4_WQ (3 * DIM * DIM / 4)
#define N4_WO (DIM * DIM / 4)
__global__ __launch_bounds__(256) void mhsa_cast_all(const float* __restrict__ x,
    const float* __restrict__ wq, const float* __restrict__ wo,
    unsigned short* __restrict__ xb, unsigned short* __restrict__ wqb,
    unsigned short* __restrict__ wob) {
  int i = blockIdx.x * 256 + threadIdx.x;
  const float* src; unsigned short* dst; int off;
  if (i < N4_X)              { src = x;  dst = xb;  off = i; }
  else if (i < N4_X + N4_WQ) { src = wq; dst = wqb; off = i - N4_X; }
  else                       { src = wo; dst = wob; off = i - (N4_X + N4_WQ); }
  float4v f = ((const float4v*)src)[off];
  u16x4 o;
  o.x = f2bf(f.x); o.y = f2bf(f.y); o.z = f2bf(f.z); o.w = f2bf(f.w);
  ((u16x4*)dst)[off] = o;
}

// ================= GEMM core v3: BK=32, dbuf, 1 barrier/iter, 3 blocks/CU =================
// XOR swizzle at 16B granularity: row of 32 elems = 4 chunks; chunk c of row r at
// slot c^(r&3). Frag b128 reads: 8 accesses/bank over 8 min cycles (conflict-free).
// Staging slab = 16 rows x 32 cols (1 KB = one wave stage16): lane l covers row l>>2,
// swizzled chunk l&3 -> global column ((l&3)^((l>>2)&3))*8.
// __launch_bounds__(256,3): cap total regs ~170 (64 AGPR + ~106 VGPR) -> 3 blocks/CU;
// grid 768 = exactly one full round, no tail; 3 resident blocks hide barrier drains.

// ---------- QKV GEMM (operand-swapped): C^T layout, packed epilogue ----------
__global__ __launch_bounds__(256, 3) void mhsa_gemm_qkv(const unsigned short* __restrict__ A,
    const unsigned short* __restrict__ Bw, const float* __restrict__ bias,
    unsigned short* __restrict__ qws, unsigned short* __restrict__ kws,
    unsigned short* __restrict__ vws) {
  __shared__ unsigned short As[2][128 * 32];
  __shared__ unsigned short Bs[2][128 * 32];
  const int t = threadIdx.x;
  const int w = t >> 6, l = t & 63;
  const int wm = w >> 1, wn = w & 1;
  const int rowBase = blockIdx.y * 128;   // tokens
  const int colBase = blockIdx.x * 128;   // e
  const int fr = l & 15, q4 = l >> 4, ln = l & 15;
  const int srow = l >> 2;                       // staging row within slab
  const int scol = ((l & 3) ^ (srow & 3)) * 8;   // swizzled global column

  f32x4 zero = {0.f, 0.f, 0.f, 0.f};
  f32x4 acc[4][4];   // [a=e-tile][b=token-tile]
  #pragma unroll
  for (int a = 0; a < 4; ++a)
    #pragma unroll
    for (int b = 0; b < 4; ++b) acc[a][b] = zero;

  // prologue: stage k-tile 0 into buf 0 (8 slabs each; wave w does slabs w*2, w*2+1)
  #pragma unroll
  for (int it = 0; it < 2; ++it) {
    const int c = w * 2 + it;
    stage16(A  + (size_t)(rowBase + c * 16 + srow) * DIM + scol, &As[0][c * 512]);
    stage16(Bw + (size_t)(colBase + c * 16 + srow) * DIM + scol, &Bs[0][c * 512]);
  }
  __syncthreads();

  for (int kt = 0; kt < DIM / 32; ++kt) {
    const int cur = kt & 1, nxt = cur ^ 1;
    if (kt + 1 < DIM / 32) {
      const int k1 = (kt + 1) * 32;
      #pragma unroll
      for (int it = 0; it < 2; ++it) {
        const int c = w * 2 + it;
        stage16(A  + (size_t)(rowBase + c * 16 + srow) * DIM + k1 + scol, &As[nxt][c * 512]);
        stage16(Bw + (size_t)(colBase + c * 16 + srow) * DIM + k1 + scol, &Bs[nxt][c * 512]);
      }
    }
    s16x8 xf[4], wf[4];
    #pragma unroll
    for (int b = 0; b < 4; ++b)
      xf[b] = *(const s16x8*)&As[cur][(wm * 64 + b * 16 + fr) * 32 + ((q4 ^ (fr & 3)) * 8)];
    #pragma unroll
    for (int a = 0; a < 4; ++a)
      wf[a] = *(const s16x8*)&Bs[cur][(wn * 64 + a * 16 + fr) * 32 + ((q4 ^ (fr & 3)) * 8)];
    #pragma unroll
    for (int a = 0; a < 4; ++a)
      #pragma unroll
      for (int b = 0; b < 4; ++b)
        acc[a][b] = __builtin_amdgcn_mfma_f32_16x16x32_bf16(wf[a], xf[b], acc[a][b], 0, 0, 0);
    __syncthreads();   // publishes nxt staging; guards cur buffer reuse next iter
  }

  const int which = colBase >> 10;   // 0=Q 1=K 2=V (block never straddles)
  const float sc = (which == 0) ? QSCALE : 1.0f;
  unsigned short* dst = (which == 0) ? qws : ((which == 1) ? kws : vws);

  #pragma unroll
  for (int a = 0; a < 4; ++a) {
    const int e0 = colBase + wn * 64 + a * 16 + q4 * 4;  // 4-aligned, 4 consecutive e
    const float4v bs4 = *(const float4v*)&bias[e0];
    const int rr0 = e0 & 1023;
    const int h = rr0 >> 6, d0 = rr0 & 63;               // d0..d0+3 within one head
    #pragma unroll
    for (int b = 0; b < 4; ++b) {
      const int tok = rowBase + wm * 64 + b * 16 + ln;
      const int bb = tok >> 11, n = tok & 2047;
      if (which != 2) {
        u16x4 pk;
        #pragma unroll
        for (int r = 0; r < 4; ++r) pk[r] = f2bf((acc[a][b][r] + bs4[r]) * sc);
        *(u16x4*)&dst[(((size_t)(bb * HEADS + h)) * SEQ + n) * HD + d0] = pk;
      } else {
        #pragma unroll
        for (int r = 0; r < 4; ++r)
          dst[(((size_t)(bb * HEADS + h)) * HD + d0 + r) * SEQ + n] =
              f2bf(acc[a][b][r] + bs4[r]);
      }
    }
  }
}

// ---------- Output GEMM (operand-swapped): 64x128 tiles, float4 epilogue ----------
__global__ __launch_bounds__(256, 3) void mhsa_gemm_out(const unsigned short* __restrict__ A,
    const unsigned short* __restrict__ Bw, const float* __restrict__ bias,
    float* __restrict__ out) {
  __shared__ unsigned short As[2][64 * 32];
  __shared__ unsigned short Bs[2][128 * 32];
  const int t = threadIdx.x;
  const int w = t >> 6, l = t & 63;
  const int wm = w >> 1, wn = w & 1;
  const int rowBase = blockIdx.y * 64;    // tokens (64-row tiles -> 512 blocks)
  const int colBase = blockIdx.x * 128;   // e
  const int fr = l & 15, q4 = l >> 4, ln = l & 15;
  const int srow = l >> 2;
  const int scol = ((l & 3) ^ (srow & 3)) * 8;

  f32x4 zero = {0.f, 0.f, 0.f, 0.f};
  f32x4 acc[4][2];   // [a=e-tile][b=token-tile]
  #pragma unroll
  for (int a = 0; a < 4; ++a)
    #pragma unroll
    for (int b = 0; b < 2; ++b) acc[a][b] = zero;

  // 12 slabs total (A:0..3, B:4..11); wave w does slabs w*3..w*3+2
  #pragma unroll
  for (int it = 0; it < 3; ++it) {
    const int s = w * 3 + it;
    if (s < 4) stage16(A  + (size_t)(rowBase + s * 16 + srow) * DIM + scol, &As[0][s * 512]);
    else       stage16(Bw + (size_t)(colBase + (s - 4) * 16 + srow) * DIM + scol, &Bs[0][(s - 4) * 512]);
  }
  __syncthreads();

  for (int kt = 0; kt < DIM / 32; ++kt) {
    const int cur = kt & 1, nxt = cur ^ 1;
    if (kt + 1 < DIM / 32) {
      const int k1 = (kt + 1) * 32;
      #pragma unroll
      for (int it = 0; it < 3; ++it) {
        const int s = w * 3 + it;
        if (s < 4) stage16(A  + (size_t)(rowBase + s * 16 + srow) * DIM + k1 + scol, &As[nxt][s * 512]);
        else       stage16(Bw + (size_t)(colBase + (s - 4) * 16 + srow) * DIM + k1 + scol, &Bs[nxt][(s - 4) * 512]);
      }
    }
    s16x8 xf[2], wf[4];
    #pragma unroll
    for (int b = 0; b < 2; ++b)
      xf[b] = *(const s16x8*)&As[cur][(wm * 32 + b * 16 + fr) * 32 + ((q4 ^ (fr & 3)) * 8)];
    #pragma unroll
    for (int a = 0; a < 4; ++a)
      wf[a] = *(const s16x8*)&Bs[cur][(wn * 64 + a * 16 + fr) * 32 + ((q4 ^ (fr & 3)) * 8)];
    #pragma unroll
    for (int a = 0; a < 4; ++a)
      #pragma unroll
      for (int b = 0; b < 2; ++b)
        acc[a][b] = __builtin_amdgcn_mfma_f32_16x16x32_bf16(wf[a], xf[b], acc[a][b], 0, 0, 0);
    __syncthreads();
  }

  #pragma unroll
  for (int a = 0; a < 4; ++a) {
    const int e0 = colBase + wn * 64 + a * 16 + q4 * 4;
    const float4v bs4 = *(const float4v*)&bias[e0];
    #pragma unroll
    for (int b = 0; b < 2; ++b) {
      const int tok = rowBase + wm * 32 + b * 16 + ln;
      float4v v;
      #pragma unroll
      for (int r = 0; r < 4; ++r) v[r] = acc[a][b][r] + bs4[r];
      *(float4v*)&out[(size_t)tok * DIM + e0] = v;
    }
  }
}

// ---------- Flash attention v5 (unchanged from round 6) ----------
__global__ __launch_bounds__(256, 2) void mhsa_attn(const unsigned short* __restrict__ q,
    const unsigned short* __restrict__ k, const unsigned short* __restrict__ vt,
    unsigned short* __restrict__ o) {
  __shared__ unsigned short QPs[4 * 32 * 72];   // per-wave 2304: Q staged (2048) then P (32x72)
  __shared__ unsigned short Ks[2][64 * 64];     // double-buffered K tile
  __shared__ unsigned short Vs[2][64 * 64];     // double-buffered V^T tile
  const int t = threadIdx.x, w = t >> 6, l = t & 63;
  const int q4 = l >> 4, ln = l & 15;
  const int bh = blockIdx.y, q0 = blockIdx.x * 128;
  const unsigned short* qb  = q  + (size_t)bh * SEQ * HD;
  const unsigned short* kb  = k  + (size_t)bh * SEQ * HD;
  const unsigned short* vtb = vt + (size_t)bh * HD * SEQ;

  const int srow = l >> 3;
  const int scol = ((l & 7) ^ srow) * 8;

  unsigned short* Pw = &QPs[w * (32 * 72)];

  #pragma unroll
  for (int it = 0; it < 4; ++it)
    stage16(qb + (size_t)(q0 + w * 32 + it * 8 + srow) * HD + scol, &Pw[it * 512]);
  #pragma unroll
  for (int it = 0; it < 2; ++it) {
    const int c = w + it * 4;
    stage16(kb  + (size_t)(c * 8 + srow) * HD + scol, &Ks[0][c * 512]);
    stage16(vtb + (size_t)(c * 8 + srow) * SEQ + scol, &Vs[0][c * 512]);
  }
  __syncthreads();   // drains Q + buf0

  s16x8 aq[2][2];
  #pragma unroll
  for (int i = 0; i < 2; ++i)
    #pragma unroll
    for (int kk = 0; kk < 2; ++kk)
      aq[i][kk] = *(const s16x8*)&Pw[(i * 16 + ln) * 64 + (((kk * 4 + q4) ^ (ln & 7)) * 8)];

  f32x4 zero = {0.f, 0.f, 0.f, 0.f};
  f32x4 accO[2][4];
  float lsum[2] = {0.f, 0.f};
  #pragma unroll
  for (int i = 0; i < 2; ++i)
    #pragma unroll
    for (int jd = 0; jd < 4; ++jd) accO[i][jd] = zero;

  for (int jt = 0; jt < SEQ / 64; ++jt) {
    const int cur = jt & 1, nxt = cur ^ 1;
    if (jt + 1 < SEQ / 64) {
      const int j1 = (jt + 1) * 64;
      #pragma unroll
      for (int it = 0; it < 2; ++it) {
        const int c = w + it * 4;
        stage16(kb  + (size_t)(j1 + c * 8 + srow) * HD + scol, &Ks[nxt][c * 512]);
        stage16(vtb + (size_t)(c * 8 + srow) * SEQ + j1 + scol, &Vs[nxt][c * 512]);
      }
    }

    // S^T = K·Q^T: A = K-frag, B = Q-frag. C: col=query(ln), row=key(q4*4+r)
    f32x4 St[4][2];
    #pragma unroll
    for (int jb = 0; jb < 4; ++jb)
      #pragma unroll
      for (int i = 0; i < 2; ++i) St[jb][i] = zero;
    #pragma unroll
    for (int jb = 0; jb < 4; ++jb) {
      s16x8 ak0 = *(const s16x8*)&Ks[cur][(jb * 16 + ln) * 64 + ((q4 ^ (ln & 7)) * 8)];
      s16x8 ak1 = *(const s16x8*)&Ks[cur][(jb * 16 + ln) * 64 + (((4 + q4) ^ (ln & 7)) * 8)];
      #pragma unroll
      for (int i = 0; i < 2; ++i) {
        St[jb][i] = __builtin_amdgcn_mfma_f32_16x16x32_bf16(ak0, aq[i][0], St[jb][i], 0, 0, 0);
        St[jb][i] = __builtin_amdgcn_mfma_f32_16x16x32_bf16(ak1, aq[i][1], St[jb][i], 0, 0, 0);
      }
    }

    // P = exp2(S), truncate; pack 4 key-consecutive bf16 -> one b64 LDS write.
    #pragma unroll
    for (int i = 0; i < 2; ++i)
      #pragma unroll
      for (int jb = 0; jb < 4; ++jb) {
        uint32_t u0 = __float_as_uint(fast_exp2(St[jb][i][0]));
        uint32_t u1 = __float_as_uint(fast_exp2(St[jb][i][1]));
        uint32_t u2 = __float_as_uint(fast_exp2(St[jb][i][2]));
        uint32_t u3 = __float_as_uint(fast_exp2(St[jb][i][3]));
        lsum[i] += __uint_as_float(u0 & 0xffff0000u) + __uint_as_float(u1 & 0xffff0000u)
                 + __uint_as_float(u2 & 0xffff0000u) + __uint_as_float(u3 & 0xffff0000u);
        u32x2 pk;
        pk.x = pack_bf16_trunc(u0, u1);
        pk.y = pack_bf16_trunc(u2, u3);
        *(u32x2*)&Pw[(i * 16 + ln) * 72 + jb * 16 + q4 * 4] = pk;
      }

    s16x8 ap[2][2];
    #pragma unroll
    for (int i = 0; i < 2; ++i)
      #pragma unroll
      for (int kk = 0; kk < 2; ++kk)
        ap[i][kk] = *(const s16x8*)&Pw[(i * 16 + ln) * 72 + kk * 32 + q4 * 8];

    #pragma unroll
    for (int jd = 0; jd < 4; ++jd) {
      s16x8 bv0 = *(const s16x8*)&Vs[cur][(jd * 16 + ln) * 64 + ((q4 ^ (ln & 7)) * 8)];
      s16x8 bv1 = *(const s16x8*)&Vs[cur][(jd * 16 + ln) * 64 + (((4 + q4) ^ (ln & 7)) * 8)];
      #pragma unroll
      for (int i = 0; i < 2; ++i) {
        accO[i][jd] = __builtin_amdgcn_mfma_f32_16x16x32_bf16(ap[i][0], bv0, accO[i][jd], 0, 0, 0);
        accO[i][jd] = __builtin_amdgcn_mfma_f32_16x16x32_bf16(ap[i][1], bv1, accO[i][jd], 0, 0, 0);
      }
    }

    __syncthreads();
  }

  const int b = bh >> 4, h = bh & 15;
  #pragma unroll
  for (int i = 0; i < 2; ++i) {
    float s = lsum[i];
    s += __shfl_xor(s, 16);
    s += __shfl_xor(s, 32);
    const float inv = 1.f / s;
    #pragma unroll
    for (int r = 0; r < 4; ++r) {
      const float invr = __shfl(inv, (l & 48) + q4 * 4 + r);
      const int row = q0 + w * 32 + i * 16 + q4 * 4 + r;
      #pragma unroll
      for (int jd = 0; jd < 4; ++jd)
        o[((size_t)(b * SEQ + row)) * DIM + h * HD + jd * 16 + ln] = f2bf(accO[i][jd][r] * invr);
    }
  }
}

// ---------- launch ----------
extern "C" void kernel_launch(void* const* d_in, const int* in_sizes, int n_in,
                              void* d_out, int out_size, void* d_ws, size_t ws_size,
                              hipStream_t stream) {
  const float* x     = (const float*)d_in[0];   // [2,2048,1024]
  const float* Wqkv  = (const float*)d_in[1];   // [3072,1024]
  const float* bqkv  = (const float*)d_in[2];   // [3072]
  const float* Wout  = (const float*)d_in[3];   // [1024,1024]
  const float* bout  = (const float*)d_in[4];   // [1024]
  float* out = (float*)d_out;

  unsigned short* ws = (unsigned short*)d_ws;
  unsigned short* x_bf    = ws;
  unsigned short* wqkv_bf = x_bf    + (size_t)TOKENS * DIM;
  unsigned short* wout_bf = wqkv_bf + (size_t)3 * DIM * DIM;
  unsigned short* q_ws    = wout_bf + (size_t)DIM * DIM;
  unsigned short* k_ws    = q_ws    + (size_t)TOKENS * DIM;
  unsigned short* v_ws    = k_ws    + (size_t)TOKENS * DIM;    // transposed [bh][d][n]
  unsigned short* ao_ws   = v_ws    + (size_t)TOKENS * DIM;

  // fused cast (one launch)
  {
    const int n4 = N4_X + N4_WQ + N4_WO;   // 2,097,152 -> 8192 blocks
    mhsa_cast_all<<<n4 / 256, 256, 0, stream>>>(x, Wqkv, Wout, x_bf, wqkv_bf, wout_bf);
  }

  // QKV projection + scatter (V transposed, Q pre-scaled)
  {
    dim3 grid(3 * DIM / 128, TOKENS / 128);   // (24, 32) = 768 blocks = 3/CU, one round
    mhsa_gemm_qkv<<<grid, 256, 0, stream>>>(x_bf, wqkv_bf, bqkv, q_ws, k_ws, v_ws);
  }

  // fused attention
  {
    dim3 grid(SEQ / 128, BATCH * HEADS);      // (16, 32), 256 threads
    mhsa_attn<<<grid, 256, 0, stream>>>(q_ws, k_ws, v_ws, ao_ws);
  }

  // output projection
  {
    dim3 grid(DIM / 128, TOKENS / 64);        // (8, 64) = 512 blocks
    mhsa_gemm_out<<<grid, 256, 0, stream>>>(ao_ws, wout_bf, bout, out);
  }
}

// Round 8
// 193.135 us; speedup vs baseline: 1.1572x; 1.0386x over previous
//
#include <hip/hip_runtime.h>
#include <stdint.h>
#include <stddef.h>

typedef __attribute__((ext_vector_type(4))) float  f32x4;
typedef __attribute__((ext_vector_type(8))) short  s16x8;
typedef __attribute__((ext_vector_type(4))) float  float4v;
typedef __attribute__((ext_vector_type(4))) unsigned short u16x4;
typedef __attribute__((ext_vector_type(2))) unsigned int   u32x2;

#define DIM    1024
#define HEADS  16
#define HD     64
#define SEQ    2048
#define BATCH  2
#define TOKENS (BATCH * SEQ)   // 4096

// 0.125 (1/sqrt(64)) * log2(e): folded into Q so softmax uses exp2 directly
#define QSCALE 0.18033688011112042f

// ---------- helpers ----------
__device__ __forceinline__ unsigned short f2bf(float f) {
  union { float f; uint32_t u; } x; x.f = f;
  uint32_t r = x.u + 0x7fffu + ((x.u >> 16) & 1u);   // RNE
  return (unsigned short)(r >> 16);
}

__device__ __forceinline__ float fast_exp2(float x) {
#if __has_builtin(__builtin_amdgcn_exp2f)
  return __builtin_amdgcn_exp2f(x);
#else
  return exp2f(x);
#endif
}

// pack high-16s of two fp32 into one dword: (hi & 0xffff0000) | (lo >> 16)
__device__ __forceinline__ uint32_t pack_bf16_trunc(uint32_t lo, uint32_t hi) {
#if __has_builtin(__builtin_amdgcn_perm)
  return __builtin_amdgcn_perm(hi, lo, 0x07060302u);
#else
  return (hi & 0xffff0000u) | (lo >> 16);
#endif
}

// async global->LDS, 16 B per lane; lds dest = base + lane*16 (wave-uniform base)
__device__ __forceinline__ void stage16(const unsigned short* gp, unsigned short* lp) {
#if __has_builtin(__builtin_amdgcn_global_load_lds)
  __builtin_amdgcn_global_load_lds((const __attribute__((address_space(1))) void*)gp,
                                   (__attribute__((address_space(3))) void*)lp, 16, 0, 0);
#else
  *(s16x8*)(lp + (threadIdx.x & 63) * 8) = *(const s16x8*)gp;
#endif
}

// ---------- fused cast fp32 -> bf16 (x, W_qkv, W_out in one launch) ----------
#define N4_X  (TOKENS * DIM / 4)
#define N4_WQ (3 * DIM * DIM / 4)
#define N4_WO (DIM * DIM / 4)
__global__ __launch_bounds__(256) void mhsa_cast_all(const float* __restrict__ x,
    const float* __restrict__ wq, const float* __restrict__ wo,
    unsigned short* __restrict__ xb, unsigned short* __restrict__ wqb,
    unsigned short* __restrict__ wob) {
  int i = blockIdx.x * 256 + threadIdx.x;
  const float* src; unsigned short* dst; int off;
  if (i < N4_X)              { src = x;  dst = xb;  off = i; }
  else if (i < N4_X + N4_WQ) { src = wq; dst = wqb; off = i - N4_X; }
  else                       { src = wo; dst = wob; off = i - (N4_X + N4_WQ); }
  float4v f = ((const float4v*)src)[off];
  u16x4 o;
  o.x = f2bf(f.x); o.y = f2bf(f.y); o.z = f2bf(f.z); o.w = f2bf(f.w);
  ((u16x4*)dst)[off] = o;
}

// ================= GEMM core v3 (unchanged from round 7) =================
// BK=32, dbuf, 1 barrier/iter, XOR-swizzled 16B chunks, 3 blocks/CU.

// ---------- QKV GEMM (operand-swapped): C^T layout, packed epilogue ----------
__global__ __launch_bounds__(256, 3) void mhsa_gemm_qkv(const unsigned short* __restrict__ A,
    const unsigned short* __restrict__ Bw, const float* __restrict__ bias,
    unsigned short* __restrict__ qws, unsigned short* __restrict__ kws,
    unsigned short* __restrict__ vws) {
  __shared__ unsigned short As[2][128 * 32];
  __shared__ unsigned short Bs[2][128 * 32];
  const int t = threadIdx.x;
  const int w = t >> 6, l = t & 63;
  const int wm = w >> 1, wn = w & 1;
  const int rowBase = blockIdx.y * 128;   // tokens
  const int colBase = blockIdx.x * 128;   // e
  const int fr = l & 15, q4 = l >> 4, ln = l & 15;
  const int srow = l >> 2;                       // staging row within slab
  const int scol = ((l & 3) ^ (srow & 3)) * 8;   // swizzled global column

  f32x4 zero = {0.f, 0.f, 0.f, 0.f};
  f32x4 acc[4][4];   // [a=e-tile][b=token-tile]
  #pragma unroll
  for (int a = 0; a < 4; ++a)
    #pragma unroll
    for (int b = 0; b < 4; ++b) acc[a][b] = zero;

  #pragma unroll
  for (int it = 0; it < 2; ++it) {
    const int c = w * 2 + it;
    stage16(A  + (size_t)(rowBase + c * 16 + srow) * DIM + scol, &As[0][c * 512]);
    stage16(Bw + (size_t)(colBase + c * 16 + srow) * DIM + scol, &Bs[0][c * 512]);
  }
  __syncthreads();

  for (int kt = 0; kt < DIM / 32; ++kt) {
    const int cur = kt & 1, nxt = cur ^ 1;
    if (kt + 1 < DIM / 32) {
      const int k1 = (kt + 1) * 32;
      #pragma unroll
      for (int it = 0; it < 2; ++it) {
        const int c = w * 2 + it;
        stage16(A  + (size_t)(rowBase + c * 16 + srow) * DIM + k1 + scol, &As[nxt][c * 512]);
        stage16(Bw + (size_t)(colBase + c * 16 + srow) * DIM + k1 + scol, &Bs[nxt][c * 512]);
      }
    }
    s16x8 xf[4], wf[4];
    #pragma unroll
    for (int b = 0; b < 4; ++b)
      xf[b] = *(const s16x8*)&As[cur][(wm * 64 + b * 16 + fr) * 32 + ((q4 ^ (fr & 3)) * 8)];
    #pragma unroll
    for (int a = 0; a < 4; ++a)
      wf[a] = *(const s16x8*)&Bs[cur][(wn * 64 + a * 16 + fr) * 32 + ((q4 ^ (fr & 3)) * 8)];
    #pragma unroll
    for (int a = 0; a < 4; ++a)
      #pragma unroll
      for (int b = 0; b < 4; ++b)
        acc[a][b] = __builtin_amdgcn_mfma_f32_16x16x32_bf16(wf[a], xf[b], acc[a][b], 0, 0, 0);
    __syncthreads();
  }

  const int which = colBase >> 10;   // 0=Q 1=K 2=V (block never straddles)
  const float sc = (which == 0) ? QSCALE : 1.0f;
  unsigned short* dst = (which == 0) ? qws : ((which == 1) ? kws : vws);

  #pragma unroll
  for (int a = 0; a < 4; ++a) {
    const int e0 = colBase + wn * 64 + a * 16 + q4 * 4;  // 4-aligned, 4 consecutive e
    const float4v bs4 = *(const float4v*)&bias[e0];
    const int rr0 = e0 & 1023;
    const int h = rr0 >> 6, d0 = rr0 & 63;               // d0..d0+3 within one head
    #pragma unroll
    for (int b = 0; b < 4; ++b) {
      const int tok = rowBase + wm * 64 + b * 16 + ln;
      const int bb = tok >> 11, n = tok & 2047;
      if (which != 2) {
        u16x4 pk;
        #pragma unroll
        for (int r = 0; r < 4; ++r) pk[r] = f2bf((acc[a][b][r] + bs4[r]) * sc);
        *(u16x4*)&dst[(((size_t)(bb * HEADS + h)) * SEQ + n) * HD + d0] = pk;
      } else {
        #pragma unroll
        for (int r = 0; r < 4; ++r)
          dst[(((size_t)(bb * HEADS + h)) * HD + d0 + r) * SEQ + n] =
              f2bf(acc[a][b][r] + bs4[r]);
      }
    }
  }
}

// ---------- Output GEMM (operand-swapped): 64x128 tiles, float4 epilogue ----------
__global__ __launch_bounds__(256, 3) void mhsa_gemm_out(const unsigned short* __restrict__ A,
    const unsigned short* __restrict__ Bw, const float* __restrict__ bias,
    float* __restrict__ out) {
  __shared__ unsigned short As[2][64 * 32];
  __shared__ unsigned short Bs[2][128 * 32];
  const int t = threadIdx.x;
  const int w = t >> 6, l = t & 63;
  const int wm = w >> 1, wn = w & 1;
  const int rowBase = blockIdx.y * 64;    // tokens (64-row tiles -> 512 blocks)
  const int colBase = blockIdx.x * 128;   // e
  const int fr = l & 15, q4 = l >> 4, ln = l & 15;
  const int srow = l >> 2;
  const int scol = ((l & 3) ^ (srow & 3)) * 8;

  f32x4 zero = {0.f, 0.f, 0.f, 0.f};
  f32x4 acc[4][2];   // [a=e-tile][b=token-tile]
  #pragma unroll
  for (int a = 0; a < 4; ++a)
    #pragma unroll
    for (int b = 0; b < 2; ++b) acc[a][b] = zero;

  #pragma unroll
  for (int it = 0; it < 3; ++it) {
    const int s = w * 3 + it;
    if (s < 4) stage16(A  + (size_t)(rowBase + s * 16 + srow) * DIM + scol, &As[0][s * 512]);
    else       stage16(Bw + (size_t)(colBase + (s - 4) * 16 + srow) * DIM + scol, &Bs[0][(s - 4) * 512]);
  }
  __syncthreads();

  for (int kt = 0; kt < DIM / 32; ++kt) {
    const int cur = kt & 1, nxt = cur ^ 1;
    if (kt + 1 < DIM / 32) {
      const int k1 = (kt + 1) * 32;
      #pragma unroll
      for (int it = 0; it < 3; ++it) {
        const int s = w * 3 + it;
        if (s < 4) stage16(A  + (size_t)(rowBase + s * 16 + srow) * DIM + k1 + scol, &As[nxt][s * 512]);
        else       stage16(Bw + (size_t)(colBase + (s - 4) * 16 + srow) * DIM + k1 + scol, &Bs[nxt][(s - 4) * 512]);
      }
    }
    s16x8 xf[2], wf[4];
    #pragma unroll
    for (int b = 0; b < 2; ++b)
      xf[b] = *(const s16x8*)&As[cur][(wm * 32 + b * 16 + fr) * 32 + ((q4 ^ (fr & 3)) * 8)];
    #pragma unroll
    for (int a = 0; a < 4; ++a)
      wf[a] = *(const s16x8*)&Bs[cur][(wn * 64 + a * 16 + fr) * 32 + ((q4 ^ (fr & 3)) * 8)];
    #pragma unroll
    for (int a = 0; a < 4; ++a)
      #pragma unroll
      for (int b = 0; b < 2; ++b)
        acc[a][b] = __builtin_amdgcn_mfma_f32_16x16x32_bf16(wf[a], xf[b], acc[a][b], 0, 0, 0);
    __syncthreads();
  }

  #pragma unroll
  for (int a = 0; a < 4; ++a) {
    const int e0 = colBase + wn * 64 + a * 16 + q4 * 4;
    const float4v bs4 = *(const float4v*)&bias[e0];
    #pragma unroll
    for (int b = 0; b < 2; ++b) {
      const int tok = rowBase + wm * 32 + b * 16 + ln;
      float4v v;
      #pragma unroll
      for (int r = 0; r < 4; ++r) v[r] = acc[a][b][r] + bs4[r];
      *(float4v*)&out[(size_t)tok * DIM + e0] = v;
    }
  }
}

// ---------- Flash attention v6: cross-iteration software pipeline ----------
// 256 threads (4 waves x 32 q-rows), K/V tiles 64, XOR-swizzled staging.
// Iter j runs TWO independent streams per wave:
//   stream A: ap_j LDS reads (P_j written LAST iter -> latency elapsed) -> PV_j MFMAs
//   stream B: K_{j+1} frag reads -> S_{j+1} MFMAs -> exp -> P_{j+1} writes
// K dbuf staged 2 AHEAD (iter j stages K_{j+2} into slot j%2; K_j reads drained at
// B_{j-1}); V dbuf staged 1 ahead as before. P single per-wave buffer: in-order LDS
// pipe + anti-dependency keeps ap_j reads before P_{j+1} writes to the same addrs.
__global__ __launch_bounds__(256, 2) void mhsa_attn(const unsigned short* __restrict__ q,
    const unsigned short* __restrict__ k, const unsigned short* __restrict__ vt,
    unsigned short* __restrict__ o) {
  __shared__ unsigned short QPs[4 * 32 * 72];   // per-wave 2304: Q staged (2048) then P (32x72)
  __shared__ unsigned short Ks[2][64 * 64];     // dbuf K tile (staged 2 ahead)
  __shared__ unsigned short Vs[2][64 * 64];     // dbuf V^T tile (staged 1 ahead)
  const int t = threadIdx.x, w = t >> 6, l = t & 63;
  const int q4 = l >> 4, ln = l & 15;
  const int bh = blockIdx.y, q0 = blockIdx.x * 128;
  const unsigned short* qb  = q  + (size_t)bh * SEQ * HD;
  const unsigned short* kb  = k  + (size_t)bh * SEQ * HD;
  const unsigned short* vtb = vt + (size_t)bh * HD * SEQ;

  const int srow = l >> 3;
  const int scol = ((l & 7) ^ srow) * 8;

  unsigned short* Pw = &QPs[w * (32 * 72)];

  // prologue staging: Q (wave-local region), K_0, V_0, K_1
  #pragma unroll
  for (int it = 0; it < 4; ++it)
    stage16(qb + (size_t)(q0 + w * 32 + it * 8 + srow) * HD + scol, &Pw[it * 512]);
  #pragma unroll
  for (int it = 0; it < 2; ++it) {
    const int c = w + it * 4;
    stage16(kb  + (size_t)(c * 8 + srow) * HD + scol,        &Ks[0][c * 512]);
    stage16(vtb + (size_t)(c * 8 + srow) * SEQ + scol,       &Vs[0][c * 512]);
    stage16(kb  + (size_t)(64 + c * 8 + srow) * HD + scol,   &Ks[1][c * 512]);
  }
  __syncthreads();   // publishes Q + K_0 + V_0 + K_1

  // hoist Q fragments; Pw region then reused for P
  s16x8 aq[2][2];
  #pragma unroll
  for (int i = 0; i < 2; ++i)
    #pragma unroll
    for (int kk = 0; kk < 2; ++kk)
      aq[i][kk] = *(const s16x8*)&Pw[(i * 16 + ln) * 64 + (((kk * 4 + q4) ^ (ln & 7)) * 8)];

  f32x4 zero = {0.f, 0.f, 0.f, 0.f};
  f32x4 accO[2][4];
  float lsum[2] = {0.f, 0.f};
  #pragma unroll
  for (int i = 0; i < 2; ++i)
    #pragma unroll
    for (int jd = 0; jd < 4; ++jd) accO[i][jd] = zero;

  // prologue compute: S_0 from Ks[0], exp, write P_0
  {
    f32x4 St[4][2];
    #pragma unroll
    for (int jb = 0; jb < 4; ++jb)
      #pragma unroll
      for (int i = 0; i < 2; ++i) St[jb][i] = zero;
    #pragma unroll
    for (int jb = 0; jb < 4; ++jb) {
      s16x8 ak0 = *(const s16x8*)&Ks[0][(jb * 16 + ln) * 64 + ((q4 ^ (ln & 7)) * 8)];
      s16x8 ak1 = *(const s16x8*)&Ks[0][(jb * 16 + ln) * 64 + (((4 + q4) ^ (ln & 7)) * 8)];
      #pragma unroll
      for (int i = 0; i < 2; ++i) {
        St[jb][i] = __builtin_amdgcn_mfma_f32_16x16x32_bf16(ak0, aq[i][0], St[jb][i], 0, 0, 0);
        St[jb][i] = __builtin_amdgcn_mfma_f32_16x16x32_bf16(ak1, aq[i][1], St[jb][i], 0, 0, 0);
      }
    }
    #pragma unroll
    for (int i = 0; i < 2; ++i)
      #pragma unroll
      for (int jb = 0; jb < 4; ++jb) {
        uint32_t u0 = __float_as_uint(fast_exp2(St[jb][i][0]));
        uint32_t u1 = __float_as_uint(fast_exp2(St[jb][i][1]));
        uint32_t u2 = __float_as_uint(fast_exp2(St[jb][i][2]));
        uint32_t u3 = __float_as_uint(fast_exp2(St[jb][i][3]));
        lsum[i] += __uint_as_float(u0 & 0xffff0000u) + __uint_as_float(u1 & 0xffff0000u)
                 + __uint_as_float(u2 & 0xffff0000u) + __uint_as_float(u3 & 0xffff0000u);
        u32x2 pk;
        pk.x = pack_bf16_trunc(u0, u1);
        pk.y = pack_bf16_trunc(u2, u3);
        *(u32x2*)&Pw[(i * 16 + ln) * 72 + jb * 16 + q4 * 4] = pk;
      }
  }
  __syncthreads();   // drains K_0 frag reads before loop iter 0 overwrites Ks[0]

  const int NT = SEQ / 64;   // 32
  for (int jt = 0; jt < NT; ++jt) {
    const int cur = jt & 1, nxt = cur ^ 1;
    // stage K_{jt+2} into slot cur (K_jt's reads drained at previous barrier);
    // stage V_{jt+1} into slot nxt (V_jt being read from slot cur)
    if (jt + 2 < NT) {
      const int j2 = (jt + 2) * 64;
      #pragma unroll
      for (int it = 0; it < 2; ++it) {
        const int c = w + it * 4;
        stage16(kb + (size_t)(j2 + c * 8 + srow) * HD + scol, &Ks[cur][c * 512]);
      }
    }
    if (jt + 1 < NT) {
      const int j1 = (jt + 1) * 64;
      #pragma unroll
      for (int it = 0; it < 2; ++it) {
        const int c = w + it * 4;
        stage16(vtb + (size_t)(c * 8 + srow) * SEQ + j1 + scol, &Vs[nxt][c * 512]);
      }
    }

    // ---- stream A: PV_jt from P_jt (written last iter) and V_jt ----
    s16x8 ap[2][2];
    #pragma unroll
    for (int i = 0; i < 2; ++i)
      #pragma unroll
      for (int kk = 0; kk < 2; ++kk)
        ap[i][kk] = *(const s16x8*)&Pw[(i * 16 + ln) * 72 + kk * 32 + q4 * 8];

    // ---- stream B: S_{jt+1} from K_{jt+1} (slot nxt) ----
    if (jt + 1 < NT) {
      f32x4 St[4][2];
      #pragma unroll
      for (int jb = 0; jb < 4; ++jb)
        #pragma unroll
        for (int i = 0; i < 2; ++i) St[jb][i] = zero;
      #pragma unroll
      for (int jb = 0; jb < 4; ++jb) {
        s16x8 ak0 = *(const s16x8*)&Ks[nxt][(jb * 16 + ln) * 64 + ((q4 ^ (ln & 7)) * 8)];
        s16x8 ak1 = *(const s16x8*)&Ks[nxt][(jb * 16 + ln) * 64 + (((4 + q4) ^ (ln & 7)) * 8)];
        #pragma unroll
        for (int i = 0; i < 2; ++i) {
          St[jb][i] = __builtin_amdgcn_mfma_f32_16x16x32_bf16(ak0, aq[i][0], St[jb][i], 0, 0, 0);
          St[jb][i] = __builtin_amdgcn_mfma_f32_16x16x32_bf16(ak1, aq[i][1], St[jb][i], 0, 0, 0);
        }
      }

      // PV_jt MFMAs (independent of St chain; fills MFMA pipe while exp runs)
      #pragma unroll
      for (int jd = 0; jd < 4; ++jd) {
        s16x8 bv0 = *(const s16x8*)&Vs[cur][(jd * 16 + ln) * 64 + ((q4 ^ (ln & 7)) * 8)];
        s16x8 bv1 = *(const s16x8*)&Vs[cur][(jd * 16 + ln) * 64 + (((4 + q4) ^ (ln & 7)) * 8)];
        #pragma unroll
        for (int i = 0; i < 2; ++i) {
          accO[i][jd] = __builtin_amdgcn_mfma_f32_16x16x32_bf16(ap[i][0], bv0, accO[i][jd], 0, 0, 0);
          accO[i][jd] = __builtin_amdgcn_mfma_f32_16x16x32_bf16(ap[i][1], bv1, accO[i][jd], 0, 0, 0);
        }
      }

      // exp -> pack -> write P_{jt+1} (anti-dep on ap reads keeps order vs Pw)
      #pragma unroll
      for (int i = 0; i < 2; ++i)
        #pragma unroll
        for (int jb = 0; jb < 4; ++jb) {
          uint32_t u0 = __float_as_uint(fast_exp2(St[jb][i][0]));
          uint32_t u1 = __float_as_uint(fast_exp2(St[jb][i][1]));
          uint32_t u2 = __float_as_uint(fast_exp2(St[jb][i][2]));
          uint32_t u3 = __float_as_uint(fast_exp2(St[jb][i][3]));
          lsum[i] += __uint_as_float(u0 & 0xffff0000u) + __uint_as_float(u1 & 0xffff0000u)
                   + __uint_as_float(u2 & 0xffff0000u) + __uint_as_float(u3 & 0xffff0000u);
          u32x2 pk;
          pk.x = pack_bf16_trunc(u0, u1);
          pk.y = pack_bf16_trunc(u2, u3);
          *(u32x2*)&Pw[(i * 16 + ln) * 72 + jb * 16 + q4 * 4] = pk;
        }
    } else {
      // last iter: only PV
      #pragma unroll
      for (int jd = 0; jd < 4; ++jd) {
        s16x8 bv0 = *(const s16x8*)&Vs[cur][(jd * 16 + ln) * 64 + ((q4 ^ (ln & 7)) * 8)];
        s16x8 bv1 = *(const s16x8*)&Vs[cur][(jd * 16 + ln) * 64 + (((4 + q4) ^ (ln & 7)) * 8)];
        #pragma unroll
        for (int i = 0; i < 2; ++i) {
          accO[i][jd] = __builtin_amdgcn_mfma_f32_16x16x32_bf16(ap[i][0], bv0, accO[i][jd], 0, 0, 0);
          accO[i][jd] = __builtin_amdgcn_mfma_f32_16x16x32_bf16(ap[i][1], bv1, accO[i][jd], 0, 0, 0);
        }
      }
    }

    __syncthreads();   // publishes staging; drains cur-slot reads before reuse
  }

  // epilogue: cross-quad row-sum reduce, redistribute inverse, normalize, store
  const int b = bh >> 4, h = bh & 15;
  #pragma unroll
  for (int i = 0; i < 2; ++i) {
    float s = lsum[i];
    s += __shfl_xor(s, 16);
    s += __shfl_xor(s, 32);
    const float inv = 1.f / s;
    #pragma unroll
    for (int r = 0; r < 4; ++r) {
      const float invr = __shfl(inv, (l & 48) + q4 * 4 + r);
      const int row = q0 + w * 32 + i * 16 + q4 * 4 + r;
      #pragma unroll
      for (int jd = 0; jd < 4; ++jd)
        o[((size_t)(b * SEQ + row)) * DIM + h * HD + jd * 16 + ln] = f2bf(accO[i][jd][r] * invr);
    }
  }
}

// ---------- launch ----------
extern "C" void kernel_launch(void* const* d_in, const int* in_sizes, int n_in,
                              void* d_out, int out_size, void* d_ws, size_t ws_size,
                              hipStream_t stream) {
  const float* x     = (const float*)d_in[0];   // [2,2048,1024]
  const float* Wqkv  = (const float*)d_in[1];   // [3072,1024]
  const float* bqkv  = (const float*)d_in[2];   // [3072]
  const float* Wout  = (const float*)d_in[3];   // [1024,1024]
  const float* bout  = (const float*)d_in[4];   // [1024]
  float* out = (float*)d_out;

  unsigned short* ws = (unsigned short*)d_ws;
  unsigned short* x_bf    = ws;
  unsigned short* wqkv_bf = x_bf    + (size_t)TOKENS * DIM;
  unsigned short* wout_bf = wqkv_bf + (size_t)3 * DIM * DIM;
  unsigned short* q_ws    = wout_bf + (size_t)DIM * DIM;
  unsigned short* k_ws    = q_ws    + (size_t)TOKENS * DIM;
  unsigned short* v_ws    = k_ws    + (size_t)TOKENS * DIM;    // transposed [bh][d][n]
  unsigned short* ao_ws   = v_ws    + (size_t)TOKENS * DIM;

  // fused cast (one launch)
  {
    const int n4 = N4_X + N4_WQ + N4_WO;   // 2,097,152 -> 8192 blocks
    mhsa_cast_all<<<n4 / 256, 256, 0, stream>>>(x, Wqkv, Wout, x_bf, wqkv_bf, wout_bf);
  }

  // QKV projection + scatter (V transposed, Q pre-scaled)
  {
    dim3 grid(3 * DIM / 128, TOKENS / 128);   // (24, 32) = 768 blocks = 3/CU, one round
    mhsa_gemm_qkv<<<grid, 256, 0, stream>>>(x_bf, wqkv_bf, bqkv, q_ws, k_ws, v_ws);
  }

  // fused attention
  {
    dim3 grid(SEQ / 128, BATCH * HEADS);      // (16, 32), 256 threads
    mhsa_attn<<<grid, 256, 0, stream>>>(q_ws, k_ws, v_ws, ao_ws);
  }

  // output projection
  {
    dim3 grid(DIM / 128, TOKENS / 64);        // (8, 64) = 512 blocks
    mhsa_gemm_out<<<grid, 256, 0, stream>>>(ao_ws, wout_bf, bout, out);
  }
}